// Round 8
// baseline (280.133 us; speedup 1.0000x reference)
//
#include <hip/hip_runtime.h>
#include <math.h>

#define NN 48
#define NP 49
#define N2 2304
#define N3 110592
#define NB 8
#define NT 20
#define NH 25      // Hermitian half: slabs 0..24
#define NSL 7      // t-slices in kB_all
#define TSL 7      // t-slices in kAB (21 = 3 x 7)

typedef float2 cplx;

// acc += d * w  (complex MAC, 4 FMA)
#define CMAC(AR, AI, D, Wv)                                        \
    AR = fmaf((D).x, (Wv).x, AR); AR = fmaf(-(D).y, (Wv).y, AR);   \
    AI = fmaf((D).x, (Wv).y, AI); AI = fmaf((D).y, (Wv).x, AI);

// dual complex MAC on float4 (A in .xy, B in .zw), 8 FMA, one twiddle
#define CMAC4(AC, D, Wv)                                             \
    (AC).x = fmaf((D).x, (Wv).x, (AC).x); (AC).x = fmaf(-(D).y, (Wv).y, (AC).x); \
    (AC).y = fmaf((D).x, (Wv).y, (AC).y); (AC).y = fmaf((D).y, (Wv).x, (AC).y); \
    (AC).z = fmaf((D).z, (Wv).x, (AC).z); (AC).z = fmaf(-(D).w, (Wv).y, (AC).z); \
    (AC).w = fmaf((D).z, (Wv).y, (AC).w); (AC).w = fmaf((D).w, (Wv).x, (AC).w);

__device__ __forceinline__ void twinit(cplx* W, int t) {
    if (t < NN) {
        float ang = -6.28318530717958647692f * (float)t / (float)NN;
        float s, c;
        sincosf(ang, &s, &c);
        W[t] = make_float2(c, s);
    }
}

// radix-3 combine (complex): X[j+16m] = sum_r w3^(rm) * (S_r * W48^(rj))
__device__ __forceinline__ void radix3_combine(
    float s0r, float s0i, float s1r, float s1i, float s2r, float s2i,
    cplx w1, cplx w2, cplx& X0, cplx& X1, cplx& X2)
{
    float y1r = s1r*w1.x - s1i*w1.y, y1i = s1r*w1.y + s1i*w1.x;
    float y2r = s2r*w2.x - s2i*w2.y, y2i = s2r*w2.y + s2i*w2.x;
    float ar = y1r + y2r, ai = y1i + y2i;
    float br = y1r - y2r, bi = y1i - y2i;
    X0 = make_float2(s0r + ar, s0i + ai);
    float mr = s0r - 0.5f*ar, mi = s0i - 0.5f*ai;
    const float h = 0.86602540378443864676f;
    X1 = make_float2(mr + h*bi, mi - h*br);
    X2 = make_float2(mr - h*bi, mi + h*br);
}

// radix-3 combine on dual-complex float4
__device__ __forceinline__ void radix3_combine4(
    float4 s0, float4 s1, float4 s2, cplx w1, cplx w2,
    float4& X0, float4& X1, float4& X2)
{
    cplx a0, a1, a2, b0, b1, b2;
    radix3_combine(s0.x, s0.y, s1.x, s1.y, s2.x, s2.y, w1, w2, a0, a1, a2);
    radix3_combine(s0.z, s0.w, s1.z, s1.w, s2.z, s2.w, w1, w2, b0, b1, b2);
    X0 = make_float4(a0.x, a0.y, b0.x, b0.y);
    X1 = make_float4(a1.x, a1.y, b1.x, b1.y);
    X2 = make_float4(a2.x, a2.y, b2.x, b2.y);
}

// ---------- float2 (cplx) radix-3 DFT helpers (kA_f / kB_f) ----------
__device__ __forceinline__ void dft_rows(cplx (*S)[NP], const cplx* W, int t, int shift) {
    const int rg = t >> 4;
    const int j  = t & 15;
    float ar[3][3], ai[3][3];
#pragma unroll
    for (int q = 0; q < 3; ++q)
#pragma unroll
        for (int r = 0; r < 3; ++r) { ar[q][r] = 0.f; ai[q][r] = 0.f; }
    const int step = 3 * j;
    int tw = 0;
#pragma unroll 4
    for (int n1 = 0; n1 < 16; ++n1) {
        cplx w = W[tw];
#pragma unroll
        for (int q = 0; q < 3; ++q) {
            const cplx* row = S[3*rg + q];
            cplx d0 = row[3*n1+0], d1 = row[3*n1+1], d2 = row[3*n1+2];
            CMAC(ar[q][0], ai[q][0], d0, w);
            CMAC(ar[q][1], ai[q][1], d1, w);
            CMAC(ar[q][2], ai[q][2], d2, w);
        }
        tw += step; if (tw >= NN) tw -= NN;
    }
    cplx w1 = W[j], w2 = W[2*j];
    __syncthreads();
    int k0 = j, k1 = j + 16, k2 = j + 32;
    if (shift) { k0 = (k0+24)%NN; k1 = (k1+24)%NN; k2 = (k2+24)%NN; }
#pragma unroll
    for (int q = 0; q < 3; ++q) {
        cplx X0, X1, X2;
        radix3_combine(ar[q][0],ai[q][0],ar[q][1],ai[q][1],ar[q][2],ai[q][2],w1,w2,X0,X1,X2);
        S[3*rg+q][k0] = X0; S[3*rg+q][k1] = X1; S[3*rg+q][k2] = X2;
    }
    __syncthreads();
}

__device__ __forceinline__ void dft_cols(cplx (*S)[NP], const cplx* W, int t, int shift) {
    const int zg = t & 15;
    const int j  = t >> 4;
    float ar[3][3], ai[3][3];
#pragma unroll
    for (int zi = 0; zi < 3; ++zi)
#pragma unroll
        for (int r = 0; r < 3; ++r) { ar[zi][r] = 0.f; ai[zi][r] = 0.f; }
    const int step = 3 * j;
    int tw = 0;
#pragma unroll 4
    for (int n1 = 0; n1 < 16; ++n1) {
        cplx w = W[tw];
#pragma unroll
        for (int r = 0; r < 3; ++r) {
            const cplx* row = S[3*n1 + r];
            cplx d0 = row[3*zg+0], d1 = row[3*zg+1], d2 = row[3*zg+2];
            CMAC(ar[0][r], ai[0][r], d0, w);
            CMAC(ar[1][r], ai[1][r], d1, w);
            CMAC(ar[2][r], ai[2][r], d2, w);
        }
        tw += step; if (tw >= NN) tw -= NN;
    }
    cplx w1 = W[j], w2 = W[2*j];
    __syncthreads();
    int k0 = j, k1 = j + 16, k2 = j + 32;
    if (shift) { k0 = (k0+24)%NN; k1 = (k1+24)%NN; k2 = (k2+24)%NN; }
#pragma unroll
    for (int zi = 0; zi < 3; ++zi) {
        cplx X0, X1, X2;
        radix3_combine(ar[zi][0],ai[zi][0],ar[zi][1],ai[zi][1],ar[zi][2],ai[zi][2],w1,w2,X0,X1,X2);
        S[k0][3*zg+zi] = X0; S[k1][3*zg+zi] = X1; S[k2][3*zg+zi] = X2;
    }
    __syncthreads();
}

// ---------- float4 (dual complex) radix-3 DFT helpers (kAB) ----------
__device__ __forceinline__ void dft_rows4(float4 (*S)[NP], const cplx* W, int t) {
    const int rg = t >> 4;
    const int j  = t & 15;
    float4 acc[3][3];
#pragma unroll
    for (int q = 0; q < 3; ++q)
#pragma unroll
        for (int r = 0; r < 3; ++r) acc[q][r] = make_float4(0.f,0.f,0.f,0.f);
    const int step = 3 * j;
    int tw = 0;
    const float4* r0 = S[3*rg + 0];
    const float4* r1 = S[3*rg + 1];
    const float4* r2 = S[3*rg + 2];
#pragma unroll 4
    for (int n1 = 0; n1 < 16; ++n1) {
        cplx w = W[tw];
        float4 d00 = r0[3*n1+0], d01 = r0[3*n1+1], d02 = r0[3*n1+2];
        float4 d10 = r1[3*n1+0], d11 = r1[3*n1+1], d12 = r1[3*n1+2];
        float4 d20 = r2[3*n1+0], d21 = r2[3*n1+1], d22 = r2[3*n1+2];
        CMAC4(acc[0][0], d00, w); CMAC4(acc[0][1], d01, w); CMAC4(acc[0][2], d02, w);
        CMAC4(acc[1][0], d10, w); CMAC4(acc[1][1], d11, w); CMAC4(acc[1][2], d12, w);
        CMAC4(acc[2][0], d20, w); CMAC4(acc[2][1], d21, w); CMAC4(acc[2][2], d22, w);
        tw += step; if (tw >= NN) tw -= NN;
    }
    cplx w1 = W[j], w2 = W[2*j];
    __syncthreads();
#pragma unroll
    for (int q = 0; q < 3; ++q) {
        float4 X0, X1, X2;
        radix3_combine4(acc[q][0], acc[q][1], acc[q][2], w1, w2, X0, X1, X2);
        S[3*rg+q][j] = X0; S[3*rg+q][j+16] = X1; S[3*rg+q][j+32] = X2;
    }
    __syncthreads();
}

__device__ __forceinline__ void dft_cols4(float4 (*S)[NP], const cplx* W, int t) {
    const int zg = t & 15;
    const int j  = t >> 4;
    float4 acc[3][3];   // [zi][r]
#pragma unroll
    for (int zi = 0; zi < 3; ++zi)
#pragma unroll
        for (int r = 0; r < 3; ++r) acc[zi][r] = make_float4(0.f,0.f,0.f,0.f);
    const int step = 3 * j;
    int tw = 0;
#pragma unroll 4
    for (int n1 = 0; n1 < 16; ++n1) {
        cplx w = W[tw];
#pragma unroll
        for (int r = 0; r < 3; ++r) {
            const float4* row = S[3*n1 + r];
            float4 d0 = row[3*zg+0], d1 = row[3*zg+1], d2 = row[3*zg+2];
            CMAC4(acc[0][r], d0, w);
            CMAC4(acc[1][r], d1, w);
            CMAC4(acc[2][r], d2, w);
        }
        tw += step; if (tw >= NN) tw -= NN;
    }
    cplx w1 = W[j], w2 = W[2*j];
    __syncthreads();
#pragma unroll
    for (int zi = 0; zi < 3; ++zi) {
        float4 X0, X1, X2;
        radix3_combine4(acc[zi][0], acc[zi][1], acc[zi][2], w1, w2, X0, X1, X2);
        S[j][3*zg+zi] = X0; S[j+16][3*zg+zi] = X1; S[j+32][3*zg+zi] = X2;
    }
    __syncthreads();
}

// f (real) -> DFT z, DFT y (both shifted)
__global__ __launch_bounds__(256)
void kA_f(const float* __restrict__ f, cplx* __restrict__ out) {
    __shared__ cplx S[NN][NP];
    __shared__ cplx W[NN];
    const int x = blockIdx.x, b = blockIdx.y, t = threadIdx.x;
    const float* src = f + (size_t)b * N3 + (size_t)x * N2;
    for (int i = t; i < N2; i += 256) S[i / NN][i % NN] = make_float2(src[i], 0.f);
    twinit(W, t);
    __syncthreads();
    dft_rows(S, W, t, 1);
    dft_cols(S, W, t, 1);
    cplx* dst = out + (size_t)b * N3 + (size_t)x * N2;
    for (int i = t; i < N2; i += 256) dst[i] = S[i / NN][i % NN];
}

// finalize f_spec: DFT x (shifted), * 1/N3, in place
__global__ __launch_bounds__(256)
void kB_f(cplx* __restrict__ vol) {
    __shared__ cplx S[NN][NP];
    __shared__ cplx W[NN];
    const int y = blockIdx.x, b = blockIdx.y, t = threadIdx.x;
    cplx* base = vol + (size_t)b * N3 + (size_t)y * NN;
    for (int i = t; i < N2; i += 256) { int xr = i / NN, z = i % NN; S[xr][z] = base[(size_t)xr * N2 + z]; }
    twinit(W, t);
    __syncthreads();
    dft_cols(S, W, t, 1);
    const float inv = 1.f / (float)N3;
    for (int i = t; i < N2; i += 256) {
        int xr = i / NN, z = i % NN;
        cplx v = S[xr][z];
        base[(size_t)xr * N2 + z] = make_float2(v.x * inv, v.y * inv);
    }
}

// Fused A-pass, persistent over t: spec slab held in registers, phi/psi
// register-prefetched for the next t while the current DFT computes.
// blockIdx.z = s (t-slice); lt = s, s+TSL, ...; ti = t0+lt; ti==NT -> fl pair.
__global__ __launch_bounds__(256)
void kAB(const cplx* __restrict__ spec,
         const float* __restrict__ phi, const float* __restrict__ psi,
         const float* __restrict__ phipsi,
         float4* __restrict__ vab, int t0, int cn) {
    __shared__ float4 S[NN][NP];
    __shared__ cplx W[NN];
    const int ix = blockIdx.x, b = blockIdx.y, s = blockIdx.z, t = threadIdx.x;
    twinit(W, t);

    // spec slab -> registers, once per block (N2 = 9*256 exactly)
    cplx sp[9];
    {
        const cplx* src = spec + (size_t)b * N3 + (size_t)ix * N2;
#pragma unroll
        for (int k = 0; k < 9; ++k) sp[k] = src[t + 256 * k];
    }

    float p[9], q[9];
    {   // prologue: load first t's multipliers
        const int ti = t0 + s;
        if (ti < NT) {
            const float* mp = phi + (size_t)ti * N3 + (size_t)ix * N2;
            const float* mq = psi + (size_t)ti * N3 + (size_t)ix * N2;
#pragma unroll
            for (int k = 0; k < 9; ++k) { p[k] = mp[t + 256 * k]; q[k] = mq[t + 256 * k]; }
        } else {
            const float* mp = phipsi + (size_t)ix * N2;
#pragma unroll
            for (int k = 0; k < 9; ++k) { p[k] = mp[t + 256 * k]; q[k] = 1.f; }
        }
    }

    for (int lt = s; lt < cn; lt += TSL) {
        // build S tile from registers (same thread writes the slots it will
        // read in the out-copy, so no extra barrier is needed across iters)
#pragma unroll
        for (int k = 0; k < 9; ++k) {
            int i = t + 256 * k;
            S[i / NN][i % NN] = make_float4(sp[k].x * p[k], sp[k].y * p[k],
                                            sp[k].x * q[k], sp[k].y * q[k]);
        }
        __syncthreads();
        // prefetch next t's multipliers; completes under the two DFT passes
        const int ltn = lt + TSL;
        if (ltn < cn) {
            const int ti = t0 + ltn;
            if (ti < NT) {
                const float* mp = phi + (size_t)ti * N3 + (size_t)ix * N2;
                const float* mq = psi + (size_t)ti * N3 + (size_t)ix * N2;
#pragma unroll
                for (int k = 0; k < 9; ++k) { p[k] = mp[t + 256 * k]; q[k] = mq[t + 256 * k]; }
            } else {
                const float* mp = phipsi + (size_t)ix * N2;
#pragma unroll
                for (int k = 0; k < 9; ++k) { p[k] = mp[t + 256 * k]; q[k] = 1.f; }
            }
        }
        dft_rows4(S, W, t);
        dft_cols4(S, W, t);
        float4* out = vab + ((size_t)(lt * NB + b) * NH + ix) * N2;
#pragma unroll
        for (int k = 0; k < 9; ++k) {
            int i = t + 256 * k;
            out[i] = S[i / NN][i % NN];
        }
    }
}

// Real-valued x-DFT via Hermitian symmetry + product + t-accumulate.
// Ah[j] = A[0] + (-1)^j A[24] + 2*sum_{n=1}^{23} Re(A[n] W48^{nj}).
// Register-prefetched tile staging (round-7, kept).
__global__ __launch_bounds__(256)
void kB_all(const float4* __restrict__ vab,
            float* __restrict__ out, const float* __restrict__ kn,
            const int* __restrict__ Mv, int t0, int cn) {
    __shared__ float4 SAB[NH][NN];   // 1200 float4, linear (2-way bank alias = free)
    __shared__ cplx W[NN];
    const int y = blockIdx.x, b = blockIdx.y, s = blockIdx.z, t = threadIdx.x;
    twinit(W, t);
    const int zg = t & 15, jg = t >> 4;
    const int i4 = 1024 + t;                 // 5th staged element index
    float4* SF = (float4*)SAB;
    float qr[3][3];
#pragma unroll
    for (int m = 0; m < 3; ++m)
#pragma unroll
        for (int zi = 0; zi < 3; ++zi) qr[m][zi] = 0.f;

    float4 R0, R1, R2, R3, R4;
    {   // prologue: stage first tile into regs
        const float4* base = vab + (size_t)(s * NB + b) * NH * N2 + (size_t)y * NN;
        R0 = base[(size_t)((t          ) / NN) * N2 + ((t          ) % NN)];
        R1 = base[(size_t)((t +  256   ) / NN) * N2 + ((t +  256   ) % NN)];
        R2 = base[(size_t)((t +  512   ) / NN) * N2 + ((t +  512   ) % NN)];
        R3 = base[(size_t)((t +  768   ) / NN) * N2 + ((t +  768   ) % NN)];
        if (i4 < NH * NN) R4 = base[(size_t)(i4 / NN) * N2 + (i4 % NN)];
    }

    for (int lt = s; lt < cn; lt += NSL) {
        const int ti = t0 + lt;
        SF[t]        = R0;
        SF[t +  256] = R1;
        SF[t +  512] = R2;
        SF[t +  768] = R3;
        if (i4 < NH * NN) SF[i4] = R4;
        __syncthreads();
        if (lt + NSL < cn) {
            const float4* base = vab + (size_t)((lt + NSL) * NB + b) * NH * N2 + (size_t)y * NN;
            R0 = base[(size_t)((t          ) / NN) * N2 + ((t          ) % NN)];
            R1 = base[(size_t)((t +  256   ) / NN) * N2 + ((t +  256   ) % NN)];
            R2 = base[(size_t)((t +  512   ) / NN) * N2 + ((t +  512   ) % NN)];
            R3 = base[(size_t)((t +  768   ) / NN) * N2 + ((t +  768   ) % NN)];
            if (i4 < NH * NN) R4 = base[(size_t)(i4 / NN) * N2 + (i4 % NN)];
        }
        float sa[3][3], sb[3][3];   // [m][zi]
#pragma unroll
        for (int m = 0; m < 3; ++m)
#pragma unroll
            for (int zi = 0; zi < 3; ++zi) { sa[m][zi] = 0.f; sb[m][zi] = 0.f; }
        int m0 = jg, m1 = jg + 16, m2 = jg + 32;
        const int s0 = jg, s1 = jg + 16, s2 = jg + 32;
        for (int n = 1; n <= 23; ++n) {
            cplx w0 = W[m0], w1 = W[m1], w2 = W[m2];
#pragma unroll
            for (int zi = 0; zi < 3; ++zi) {
                float4 d = SAB[n][3 * zg + zi];
                sa[0][zi] = fmaf(d.x, w0.x, sa[0][zi]); sa[0][zi] = fmaf(-d.y, w0.y, sa[0][zi]);
                sa[1][zi] = fmaf(d.x, w1.x, sa[1][zi]); sa[1][zi] = fmaf(-d.y, w1.y, sa[1][zi]);
                sa[2][zi] = fmaf(d.x, w2.x, sa[2][zi]); sa[2][zi] = fmaf(-d.y, w2.y, sa[2][zi]);
                sb[0][zi] = fmaf(d.z, w0.x, sb[0][zi]); sb[0][zi] = fmaf(-d.w, w0.y, sb[0][zi]);
                sb[1][zi] = fmaf(d.z, w1.x, sb[1][zi]); sb[1][zi] = fmaf(-d.w, w1.y, sb[1][zi]);
                sb[2][zi] = fmaf(d.z, w2.x, sb[2][zi]); sb[2][zi] = fmaf(-d.w, w2.y, sb[2][zi]);
            }
            m0 += s0; if (m0 >= NN) m0 -= NN;
            m1 += s1; if (m1 >= NN) m1 -= NN;
            m2 += s2; if (m2 >= NN) m2 -= NN;
        }
        const float sgn = (jg & 1) ? -1.f : 1.f;   // j = jg+16m, parity(j)=parity(jg)
        const float wgt = (ti == NT) ? -1.f : 1.f;
#pragma unroll
        for (int zi = 0; zi < 3; ++zi) {
            float4 e0  = SAB[0][3 * zg + zi];
            float4 e24 = SAB[24][3 * zg + zi];
            float basea = e0.x + sgn * e24.x;
            float baseb = e0.z + sgn * e24.z;
#pragma unroll
            for (int m = 0; m < 3; ++m) {
                float Ah = basea + 2.f * sa[m][zi];
                float Bh = baseb + 2.f * sb[m][zi];
                qr[m][zi] += wgt * Ah * Bh;
            }
        }
        __syncthreads();   // protect SAB before next iteration's ds_write
    }
    float mf = (float)(Mv[0] * Mv[0]);
    float scale = 4.f * 3.14159265358979323846f * 3.14159265358979323846f / (kn[0] * mf);
#pragma unroll
    for (int m = 0; m < 3; ++m) {
        int j = jg + 16 * m;
#pragma unroll
        for (int zi = 0; zi < 3; ++zi) {
            int z = 3 * zg + zi;
            size_t idx = (size_t)b * N3 + (size_t)j * N2 + (size_t)y * NN + z;
            atomicAdd(&out[idx], scale * qr[m][zi]);
        }
    }
}

extern "C" void kernel_launch(void* const* d_in, const int* in_sizes, int n_in,
                              void* d_out, int out_size, void* d_ws, size_t ws_size,
                              hipStream_t stream) {
    const float* f      = (const float*)d_in[0];
    const float* kn     = (const float*)d_in[1];
    const float* phi    = (const float*)d_in[2];
    const float* psi    = (const float*)d_in[3];
    const float* phipsi = (const float*)d_in[4];
    const int*   Mv     = (const int*)d_in[5];
    float* out = (float*)d_out;

    char* w = (char*)d_ws;
    const size_t fspecB = (size_t)NB * N3 * sizeof(cplx);            // 7,077,888
    const size_t perTB  = (size_t)NB * NH * N2 * sizeof(float4);     // 7,372,800 per t
    cplx* fspec = (cplx*)w;
    char* pool  = w + fspecB;

    const int NTOT = NT + 1;   // 20 fg terms + 1 fl term
    size_t avail = (ws_size > fspecB) ? (ws_size - fspecB) : 0;
    int chunk = (int)(avail / perTB);
    if (chunk < 1)    chunk = 1;
    if (chunk > NTOT) chunk = NTOT;
    float4* vab = (float4*)pool;

    hipMemsetAsync(out, 0, (size_t)NB * N3 * sizeof(float), stream);

    kA_f<<<dim3(NN, NB), 256, 0, stream>>>(f, fspec);
    kB_f<<<dim3(NN, NB), 256, 0, stream>>>(fspec);

    for (int t0 = 0; t0 < NTOT; t0 += chunk) {
        int cn = (t0 + chunk <= NTOT) ? chunk : (NTOT - t0);
        int zk = (cn < TSL) ? cn : TSL;
        kAB<<<dim3(NH, NB, zk), 256, 0, stream>>>(fspec, phi, psi, phipsi, vab, t0, cn);
        int zb = (cn < NSL) ? cn : NSL;
        kB_all<<<dim3(NN, NB, zb), 256, 0, stream>>>(vab, out, kn, Mv, t0, cn);
    }
}

// Round 10
// 270.647 us; speedup vs baseline: 1.0351x; 1.0351x over previous
//
#include <hip/hip_runtime.h>
#include <math.h>

#define NN 48
#define NP 49
#define N2 2304
#define N3 110592
#define NB 8
#define NT 20
#define NH 25          // Hermitian half: slabs 0..24
#define NHN2 57600     // NH * N2
#define NSL 7          // t-slices in kB_all

typedef float2 cplx;

// acc += d * w  (complex MAC, 4 FMA)
#define CMAC(AR, AI, D, Wv)                                        \
    AR = fmaf((D).x, (Wv).x, AR); AR = fmaf(-(D).y, (Wv).y, AR);   \
    AI = fmaf((D).x, (Wv).y, AI); AI = fmaf((D).y, (Wv).x, AI);

// dual complex MAC on float4 (A in .xy, B in .zw), 8 FMA, one twiddle
#define CMAC4(AC, D, Wv)                                             \
    (AC).x = fmaf((D).x, (Wv).x, (AC).x); (AC).x = fmaf(-(D).y, (Wv).y, (AC).x); \
    (AC).y = fmaf((D).x, (Wv).y, (AC).y); (AC).y = fmaf((D).y, (Wv).x, (AC).y); \
    (AC).z = fmaf((D).z, (Wv).x, (AC).z); (AC).z = fmaf(-(D).w, (Wv).y, (AC).z); \
    (AC).w = fmaf((D).z, (Wv).y, (AC).w); (AC).w = fmaf((D).w, (Wv).x, (AC).w);

__device__ __forceinline__ void twinit(cplx* W, int t) {
    if (t < NN) {
        float ang = -6.28318530717958647692f * (float)t / (float)NN;
        float s, c;
        sincosf(ang, &s, &c);
        W[t] = make_float2(c, s);
    }
}

// radix-3 combine (complex): X[j+16m] = sum_r w3^(rm) * (S_r * W48^(rj))
__device__ __forceinline__ void radix3_combine(
    float s0r, float s0i, float s1r, float s1i, float s2r, float s2i,
    cplx w1, cplx w2, cplx& X0, cplx& X1, cplx& X2)
{
    float y1r = s1r*w1.x - s1i*w1.y, y1i = s1r*w1.y + s1i*w1.x;
    float y2r = s2r*w2.x - s2i*w2.y, y2i = s2r*w2.y + s2i*w2.x;
    float ar = y1r + y2r, ai = y1i + y2i;
    float br = y1r - y2r, bi = y1i - y2i;
    X0 = make_float2(s0r + ar, s0i + ai);
    float mr = s0r - 0.5f*ar, mi = s0i - 0.5f*ai;
    const float h = 0.86602540378443864676f;
    X1 = make_float2(mr + h*bi, mi - h*br);
    X2 = make_float2(mr - h*bi, mi + h*br);
}

// radix-3 combine on dual-complex float4
__device__ __forceinline__ void radix3_combine4(
    float4 s0, float4 s1, float4 s2, cplx w1, cplx w2,
    float4& X0, float4& X1, float4& X2)
{
    cplx a0, a1, a2, b0, b1, b2;
    radix3_combine(s0.x, s0.y, s1.x, s1.y, s2.x, s2.y, w1, w2, a0, a1, a2);
    radix3_combine(s0.z, s0.w, s1.z, s1.w, s2.z, s2.w, w1, w2, b0, b1, b2);
    X0 = make_float4(a0.x, a0.y, b0.x, b0.y);
    X1 = make_float4(a1.x, a1.y, b1.x, b1.y);
    X2 = make_float4(a2.x, a2.y, b2.x, b2.y);
}

// ---------- float2 (cplx) radix-3 DFT helpers (kA_f / kB_f) ----------
__device__ __forceinline__ void dft_rows(cplx (*S)[NP], const cplx* W, int t, int shift) {
    const int rg = t >> 4;
    const int j  = t & 15;
    float ar[3][3], ai[3][3];
#pragma unroll
    for (int q = 0; q < 3; ++q)
#pragma unroll
        for (int r = 0; r < 3; ++r) { ar[q][r] = 0.f; ai[q][r] = 0.f; }
    const int step = 3 * j;
    int tw = 0;
#pragma unroll 4
    for (int n1 = 0; n1 < 16; ++n1) {
        cplx w = W[tw];
#pragma unroll
        for (int q = 0; q < 3; ++q) {
            const cplx* row = S[3*rg + q];
            cplx d0 = row[3*n1+0], d1 = row[3*n1+1], d2 = row[3*n1+2];
            CMAC(ar[q][0], ai[q][0], d0, w);
            CMAC(ar[q][1], ai[q][1], d1, w);
            CMAC(ar[q][2], ai[q][2], d2, w);
        }
        tw += step; if (tw >= NN) tw -= NN;
    }
    cplx w1 = W[j], w2 = W[2*j];
    __syncthreads();
    int k0 = j, k1 = j + 16, k2 = j + 32;
    if (shift) { k0 = (k0+24)%NN; k1 = (k1+24)%NN; k2 = (k2+24)%NN; }
#pragma unroll
    for (int q = 0; q < 3; ++q) {
        cplx X0, X1, X2;
        radix3_combine(ar[q][0],ai[q][0],ar[q][1],ai[q][1],ar[q][2],ai[q][2],w1,w2,X0,X1,X2);
        S[3*rg+q][k0] = X0; S[3*rg+q][k1] = X1; S[3*rg+q][k2] = X2;
    }
    __syncthreads();
}

__device__ __forceinline__ void dft_cols(cplx (*S)[NP], const cplx* W, int t, int shift) {
    const int zg = t & 15;
    const int j  = t >> 4;
    float ar[3][3], ai[3][3];
#pragma unroll
    for (int zi = 0; zi < 3; ++zi)
#pragma unroll
        for (int r = 0; r < 3; ++r) { ar[zi][r] = 0.f; ai[zi][r] = 0.f; }
    const int step = 3 * j;
    int tw = 0;
#pragma unroll 4
    for (int n1 = 0; n1 < 16; ++n1) {
        cplx w = W[tw];
#pragma unroll
        for (int r = 0; r < 3; ++r) {
            const cplx* row = S[3*n1 + r];
            cplx d0 = row[3*zg+0], d1 = row[3*zg+1], d2 = row[3*zg+2];
            CMAC(ar[0][r], ai[0][r], d0, w);
            CMAC(ar[1][r], ai[1][r], d1, w);
            CMAC(ar[2][r], ai[2][r], d2, w);
        }
        tw += step; if (tw >= NN) tw -= NN;
    }
    cplx w1 = W[j], w2 = W[2*j];
    __syncthreads();
    int k0 = j, k1 = j + 16, k2 = j + 32;
    if (shift) { k0 = (k0+24)%NN; k1 = (k1+24)%NN; k2 = (k2+24)%NN; }
#pragma unroll
    for (int zi = 0; zi < 3; ++zi) {
        cplx X0, X1, X2;
        radix3_combine(ar[zi][0],ai[zi][0],ar[zi][1],ai[zi][1],ar[zi][2],ai[zi][2],w1,w2,X0,X1,X2);
        S[k0][3*zg+zi] = X0; S[k1][3*zg+zi] = X1; S[k2][3*zg+zi] = X2;
    }
    __syncthreads();
}

// ---------- float4 (dual complex) radix-3 DFT helpers (kAB) ----------
__device__ __forceinline__ void dft_rows4(float4 (*S)[NP], const cplx* W, int t) {
    const int rg = t >> 4;
    const int j  = t & 15;
    float4 acc[3][3];
#pragma unroll
    for (int q = 0; q < 3; ++q)
#pragma unroll
        for (int r = 0; r < 3; ++r) acc[q][r] = make_float4(0.f,0.f,0.f,0.f);
    const int step = 3 * j;
    int tw = 0;
    const float4* r0 = S[3*rg + 0];
    const float4* r1 = S[3*rg + 1];
    const float4* r2 = S[3*rg + 2];
#pragma unroll 4
    for (int n1 = 0; n1 < 16; ++n1) {
        cplx w = W[tw];
        float4 d00 = r0[3*n1+0], d01 = r0[3*n1+1], d02 = r0[3*n1+2];
        float4 d10 = r1[3*n1+0], d11 = r1[3*n1+1], d12 = r1[3*n1+2];
        float4 d20 = r2[3*n1+0], d21 = r2[3*n1+1], d22 = r2[3*n1+2];
        CMAC4(acc[0][0], d00, w); CMAC4(acc[0][1], d01, w); CMAC4(acc[0][2], d02, w);
        CMAC4(acc[1][0], d10, w); CMAC4(acc[1][1], d11, w); CMAC4(acc[1][2], d12, w);
        CMAC4(acc[2][0], d20, w); CMAC4(acc[2][1], d21, w); CMAC4(acc[2][2], d22, w);
        tw += step; if (tw >= NN) tw -= NN;
    }
    cplx w1 = W[j], w2 = W[2*j];
    __syncthreads();
#pragma unroll
    for (int q = 0; q < 3; ++q) {
        float4 X0, X1, X2;
        radix3_combine4(acc[q][0], acc[q][1], acc[q][2], w1, w2, X0, X1, X2);
        S[3*rg+q][j] = X0; S[3*rg+q][j+16] = X1; S[3*rg+q][j+32] = X2;
    }
    __syncthreads();
}

__device__ __forceinline__ void dft_cols4(float4 (*S)[NP], const cplx* W, int t) {
    const int zg = t & 15;
    const int j  = t >> 4;
    float4 acc[3][3];   // [zi][r]
#pragma unroll
    for (int zi = 0; zi < 3; ++zi)
#pragma unroll
        for (int r = 0; r < 3; ++r) acc[zi][r] = make_float4(0.f,0.f,0.f,0.f);
    const int step = 3 * j;
    int tw = 0;
#pragma unroll 4
    for (int n1 = 0; n1 < 16; ++n1) {
        cplx w = W[tw];
#pragma unroll
        for (int r = 0; r < 3; ++r) {
            const float4* row = S[3*n1 + r];
            float4 d0 = row[3*zg+0], d1 = row[3*zg+1], d2 = row[3*zg+2];
            CMAC4(acc[0][r], d0, w);
            CMAC4(acc[1][r], d1, w);
            CMAC4(acc[2][r], d2, w);
        }
        tw += step; if (tw >= NN) tw -= NN;
    }
    cplx w1 = W[j], w2 = W[2*j];
    __syncthreads();
#pragma unroll
    for (int zi = 0; zi < 3; ++zi) {
        float4 X0, X1, X2;
        radix3_combine4(acc[zi][0], acc[zi][1], acc[zi][2], w1, w2, X0, X1, X2);
        S[j][3*zg+zi] = X0; S[j+16][3*zg+zi] = X1; S[j+32][3*zg+zi] = X2;
    }
    __syncthreads();
}

// f (real) -> DFT z, DFT y (both shifted)
__global__ __launch_bounds__(256)
void kA_f(const float* __restrict__ f, cplx* __restrict__ out) {
    __shared__ cplx S[NN][NP];
    __shared__ cplx W[NN];
    const int x = blockIdx.x, b = blockIdx.y, t = threadIdx.x;
    const float* src = f + (size_t)b * N3 + (size_t)x * N2;
    for (int i = t; i < N2; i += 256) S[i / NN][i % NN] = make_float2(src[i], 0.f);
    twinit(W, t);
    __syncthreads();
    dft_rows(S, W, t, 1);
    dft_cols(S, W, t, 1);
    cplx* dst = out + (size_t)b * N3 + (size_t)x * N2;
    for (int i = t; i < N2; i += 256) dst[i] = S[i / NN][i % NN];
}

// finalize f_spec: DFT x (shifted), * 1/N3; write ONLY the Hermitian half
// (ix = 0..24) into the compact spec_h[b][ix][y][z] layout.
__global__ __launch_bounds__(256)
void kB_f(const cplx* __restrict__ vol, cplx* __restrict__ outh) {
    __shared__ cplx S[NN][NP];
    __shared__ cplx W[NN];
    const int y = blockIdx.x, b = blockIdx.y, t = threadIdx.x;
    const cplx* base = vol + (size_t)b * N3 + (size_t)y * NN;
    for (int i = t; i < N2; i += 256) { int xr = i / NN, z = i % NN; S[xr][z] = base[(size_t)xr * N2 + z]; }
    twinit(W, t);
    __syncthreads();
    dft_cols(S, W, t, 1);
    const float inv = 1.f / (float)N3;
    cplx* dst = outh + (size_t)b * NHN2 + (size_t)y * NN;
    for (int i = t; i < NH * NN; i += 256) {
        int xr = i / NN, z = i % NN;
        cplx v = S[xr][z];
        dst[(size_t)xr * N2 + z] = make_float2(v.x * inv, v.y * inv);
    }
}

// Fused A-pass: va = F2(spec*phi), vb = F2(spec*psi) as dual-complex float4.
// blockIdx.z = lt; ti = t0+lt; ti==NT -> fl pair (phipsi, identity).
// spec is the compact Hermitian-half layout [b][ix<25][y][z].
__global__ __launch_bounds__(256)
void kAB(const cplx* __restrict__ spec,
         const float* __restrict__ phi, const float* __restrict__ psi,
         const float* __restrict__ phipsi,
         float4* __restrict__ vab, int t0) {
    __shared__ float4 S[NN][NP];
    __shared__ cplx W[NN];
    const int ix = blockIdx.x, b = blockIdx.y, lt = blockIdx.z, t = threadIdx.x;
    const int ti = t0 + lt;
    const cplx* src = spec + (size_t)b * NHN2 + (size_t)ix * N2;
    const float* mp;
    const float* mq;
    if (ti < NT) { mp = phi + (size_t)ti * N3 + (size_t)ix * N2; mq = psi + (size_t)ti * N3 + (size_t)ix * N2; }
    else         { mp = phipsi + (size_t)ix * N2;               mq = (const float*)nullptr; }
    for (int i = t; i < N2; i += 256) {
        cplx v = src[i];
        float p = mp[i];
        float q = mq ? mq[i] : 1.f;
        S[i / NN][i % NN] = make_float4(v.x * p, v.y * p, v.x * q, v.y * q);
    }
    twinit(W, t);
    __syncthreads();
    dft_rows4(S, W, t);
    dft_cols4(S, W, t);
    float4* out = vab + ((size_t)(lt * NB + b) * NH + ix) * N2;
    for (int i = t; i < N2; i += 256) out[i] = S[i / NN][i % NN];
}

// Real-valued x-DFT via Hermitian symmetry + product + t-accumulate.
// Ah[j] = A[0] + (-1)^j A[24] + 2*sum_{n=1}^{23} Re(A[n] W48^{nj}).
// Register-prefetched tile staging (round-7, kept).
__global__ __launch_bounds__(256)
void kB_all(const float4* __restrict__ vab,
            float* __restrict__ out, const float* __restrict__ kn,
            const int* __restrict__ Mv, int t0, int cn) {
    __shared__ float4 SAB[NH][NN];   // 1200 float4, linear (2-way bank alias = free)
    __shared__ cplx W[NN];
    const int y = blockIdx.x, b = blockIdx.y, s = blockIdx.z, t = threadIdx.x;
    twinit(W, t);
    const int zg = t & 15, jg = t >> 4;
    const int i4 = 1024 + t;                 // 5th staged element index
    float4* SF = (float4*)SAB;
    float qr[3][3];
#pragma unroll
    for (int m = 0; m < 3; ++m)
#pragma unroll
        for (int zi = 0; zi < 3; ++zi) qr[m][zi] = 0.f;

    float4 R0, R1, R2, R3, R4;
    {   // prologue: stage first tile into regs
        const float4* base = vab + (size_t)(s * NB + b) * NH * N2 + (size_t)y * NN;
        R0 = base[(size_t)((t          ) / NN) * N2 + ((t          ) % NN)];
        R1 = base[(size_t)((t +  256   ) / NN) * N2 + ((t +  256   ) % NN)];
        R2 = base[(size_t)((t +  512   ) / NN) * N2 + ((t +  512   ) % NN)];
        R3 = base[(size_t)((t +  768   ) / NN) * N2 + ((t +  768   ) % NN)];
        if (i4 < NH * NN) R4 = base[(size_t)(i4 / NN) * N2 + (i4 % NN)];
    }

    for (int lt = s; lt < cn; lt += NSL) {
        const int ti = t0 + lt;
        SF[t]        = R0;
        SF[t +  256] = R1;
        SF[t +  512] = R2;
        SF[t +  768] = R3;
        if (i4 < NH * NN) SF[i4] = R4;
        __syncthreads();
        if (lt + NSL < cn) {
            const float4* base = vab + (size_t)((lt + NSL) * NB + b) * NH * N2 + (size_t)y * NN;
            R0 = base[(size_t)((t          ) / NN) * N2 + ((t          ) % NN)];
            R1 = base[(size_t)((t +  256   ) / NN) * N2 + ((t +  256   ) % NN)];
            R2 = base[(size_t)((t +  512   ) / NN) * N2 + ((t +  512   ) % NN)];
            R3 = base[(size_t)((t +  768   ) / NN) * N2 + ((t +  768   ) % NN)];
            if (i4 < NH * NN) R4 = base[(size_t)(i4 / NN) * N2 + (i4 % NN)];
        }
        float sa[3][3], sb[3][3];   // [m][zi]
#pragma unroll
        for (int m = 0; m < 3; ++m)
#pragma unroll
            for (int zi = 0; zi < 3; ++zi) { sa[m][zi] = 0.f; sb[m][zi] = 0.f; }
        int m0 = jg, m1 = jg + 16, m2 = jg + 32;
        const int s0 = jg, s1 = jg + 16, s2 = jg + 32;
        for (int n = 1; n <= 23; ++n) {
            cplx w0 = W[m0], w1 = W[m1], w2 = W[m2];
#pragma unroll
            for (int zi = 0; zi < 3; ++zi) {
                float4 d = SAB[n][3 * zg + zi];
                sa[0][zi] = fmaf(d.x, w0.x, sa[0][zi]); sa[0][zi] = fmaf(-d.y, w0.y, sa[0][zi]);
                sa[1][zi] = fmaf(d.x, w1.x, sa[1][zi]); sa[1][zi] = fmaf(-d.y, w1.y, sa[1][zi]);
                sa[2][zi] = fmaf(d.x, w2.x, sa[2][zi]); sa[2][zi] = fmaf(-d.y, w2.y, sa[2][zi]);
                sb[0][zi] = fmaf(d.z, w0.x, sb[0][zi]); sb[0][zi] = fmaf(-d.w, w0.y, sb[0][zi]);
                sb[1][zi] = fmaf(d.z, w1.x, sb[1][zi]); sb[1][zi] = fmaf(-d.w, w1.y, sb[1][zi]);
                sb[2][zi] = fmaf(d.z, w2.x, sb[2][zi]); sb[2][zi] = fmaf(-d.w, w2.y, sb[2][zi]);
            }
            m0 += s0; if (m0 >= NN) m0 -= NN;
            m1 += s1; if (m1 >= NN) m1 -= NN;
            m2 += s2; if (m2 >= NN) m2 -= NN;
        }
        const float sgn = (jg & 1) ? -1.f : 1.f;   // j = jg+16m, parity(j)=parity(jg)
        const float wgt = (ti == NT) ? -1.f : 1.f;
#pragma unroll
        for (int zi = 0; zi < 3; ++zi) {
            float4 e0  = SAB[0][3 * zg + zi];
            float4 e24 = SAB[24][3 * zg + zi];
            float basea = e0.x + sgn * e24.x;
            float baseb = e0.z + sgn * e24.z;
#pragma unroll
            for (int m = 0; m < 3; ++m) {
                float Ah = basea + 2.f * sa[m][zi];
                float Bh = baseb + 2.f * sb[m][zi];
                qr[m][zi] += wgt * Ah * Bh;
            }
        }
        __syncthreads();   // protect SAB before next iteration's ds_write
    }
    float mf = (float)(Mv[0] * Mv[0]);
    float scale = 4.f * 3.14159265358979323846f * 3.14159265358979323846f / (kn[0] * mf);
#pragma unroll
    for (int m = 0; m < 3; ++m) {
        int j = jg + 16 * m;
#pragma unroll
        for (int zi = 0; zi < 3; ++zi) {
            int z = 3 * zg + zi;
            size_t idx = (size_t)b * N3 + (size_t)j * N2 + (size_t)y * NN + z;
            atomicAdd(&out[idx], scale * qr[m][zi]);
        }
    }
}

extern "C" void kernel_launch(void* const* d_in, const int* in_sizes, int n_in,
                              void* d_out, int out_size, void* d_ws, size_t ws_size,
                              hipStream_t stream) {
    const float* f      = (const float*)d_in[0];
    const float* kn     = (const float*)d_in[1];
    const float* phi    = (const float*)d_in[2];
    const float* psi    = (const float*)d_in[3];
    const float* phipsi = (const float*)d_in[4];
    const int*   Mv     = (const int*)d_in[5];
    float* out = (float*)d_out;

    char* w = (char*)d_ws;
    const size_t fspecB = (size_t)NB * N3 * sizeof(cplx);            // 7,077,888
    const size_t spechB = (size_t)NB * NHN2 * sizeof(cplx);          // 3,686,400
    const size_t perTB  = (size_t)NB * NH * N2 * sizeof(float4);     // 7,372,800 per t
    cplx* fspec = (cplx*)w;
    cplx* spech = (cplx*)(w + fspecB);
    char* pool  = w + fspecB + spechB;

    const int NTOT = NT + 1;   // 20 fg terms + 1 fl term
    size_t head = fspecB + spechB;
    size_t avail = (ws_size > head) ? (ws_size - head) : 0;
    int chunk = (int)(avail / perTB);
    if (chunk < 1)    chunk = 1;
    if (chunk > NTOT) chunk = NTOT;
    float4* vab = (float4*)pool;

    hipMemsetAsync(out, 0, (size_t)NB * N3 * sizeof(float), stream);

    kA_f<<<dim3(NN, NB), 256, 0, stream>>>(f, fspec);
    kB_f<<<dim3(NN, NB), 256, 0, stream>>>(fspec, spech);

    for (int t0 = 0; t0 < NTOT; t0 += chunk) {
        int cn = (t0 + chunk <= NTOT) ? chunk : (NTOT - t0);
        kAB<<<dim3(NH, NB, cn), 256, 0, stream>>>(spech, phi, psi, phipsi, vab, t0);
        int zb = (cn < NSL) ? cn : NSL;
        kB_all<<<dim3(NN, NB, zb), 256, 0, stream>>>(vab, out, kn, Mv, t0, cn);
    }
}

// Round 11
// 270.236 us; speedup vs baseline: 1.0366x; 1.0015x over previous
//
#include <hip/hip_runtime.h>
#include <math.h>

#define NN 48
#define NP 49
#define N2 2304
#define N3 110592
#define NB 8
#define NT 20
#define NH 25          // Hermitian half: slabs 0..24
#define NHN2 57600     // NH * N2
#define NSL 7          // t-slices in kB_all

typedef float2 cplx;

// acc += d * w  (complex MAC, 4 FMA)
#define CMAC(AR, AI, D, Wv)                                        \
    AR = fmaf((D).x, (Wv).x, AR); AR = fmaf(-(D).y, (Wv).y, AR);   \
    AI = fmaf((D).x, (Wv).y, AI); AI = fmaf((D).y, (Wv).x, AI);

// dual complex MAC on float4 (A in .xy, B in .zw), 8 FMA, one twiddle
#define CMAC4(AC, D, Wv)                                             \
    (AC).x = fmaf((D).x, (Wv).x, (AC).x); (AC).x = fmaf(-(D).y, (Wv).y, (AC).x); \
    (AC).y = fmaf((D).x, (Wv).y, (AC).y); (AC).y = fmaf((D).y, (Wv).x, (AC).y); \
    (AC).z = fmaf((D).z, (Wv).x, (AC).z); (AC).z = fmaf(-(D).w, (Wv).y, (AC).z); \
    (AC).w = fmaf((D).z, (Wv).y, (AC).w); (AC).w = fmaf((D).w, (Wv).x, (AC).w);

__device__ __forceinline__ void twinit(cplx* W, int t) {
    if (t < NN) {
        float ang = -6.28318530717958647692f * (float)t / (float)NN;
        float s, c;
        sincosf(ang, &s, &c);
        W[t] = make_float2(c, s);
    }
}

// radix-3 combine (complex): X[j+16m] = sum_r w3^(rm) * (S_r * W48^(rj))
__device__ __forceinline__ void radix3_combine(
    float s0r, float s0i, float s1r, float s1i, float s2r, float s2i,
    cplx w1, cplx w2, cplx& X0, cplx& X1, cplx& X2)
{
    float y1r = s1r*w1.x - s1i*w1.y, y1i = s1r*w1.y + s1i*w1.x;
    float y2r = s2r*w2.x - s2i*w2.y, y2i = s2r*w2.y + s2i*w2.x;
    float ar = y1r + y2r, ai = y1i + y2i;
    float br = y1r - y2r, bi = y1i - y2i;
    X0 = make_float2(s0r + ar, s0i + ai);
    float mr = s0r - 0.5f*ar, mi = s0i - 0.5f*ai;
    const float h = 0.86602540378443864676f;
    X1 = make_float2(mr + h*bi, mi - h*br);
    X2 = make_float2(mr - h*bi, mi + h*br);
}

// radix-3 combine on dual-complex float4
__device__ __forceinline__ void radix3_combine4(
    float4 s0, float4 s1, float4 s2, cplx w1, cplx w2,
    float4& X0, float4& X1, float4& X2)
{
    cplx a0, a1, a2, b0, b1, b2;
    radix3_combine(s0.x, s0.y, s1.x, s1.y, s2.x, s2.y, w1, w2, a0, a1, a2);
    radix3_combine(s0.z, s0.w, s1.z, s1.w, s2.z, s2.w, w1, w2, b0, b1, b2);
    X0 = make_float4(a0.x, a0.y, b0.x, b0.y);
    X1 = make_float4(a1.x, a1.y, b1.x, b1.y);
    X2 = make_float4(a2.x, a2.y, b2.x, b2.y);
}

// ---------- float2 (cplx) radix-3 DFT helpers ----------
__device__ __forceinline__ void dft_rows(cplx (*S)[NP], const cplx* W, int t, int shift) {
    const int rg = t >> 4;
    const int j  = t & 15;
    float ar[3][3], ai[3][3];
#pragma unroll
    for (int q = 0; q < 3; ++q)
#pragma unroll
        for (int r = 0; r < 3; ++r) { ar[q][r] = 0.f; ai[q][r] = 0.f; }
    const int step = 3 * j;
    int tw = 0;
#pragma unroll 4
    for (int n1 = 0; n1 < 16; ++n1) {
        cplx w = W[tw];
#pragma unroll
        for (int q = 0; q < 3; ++q) {
            const cplx* row = S[3*rg + q];
            cplx d0 = row[3*n1+0], d1 = row[3*n1+1], d2 = row[3*n1+2];
            CMAC(ar[q][0], ai[q][0], d0, w);
            CMAC(ar[q][1], ai[q][1], d1, w);
            CMAC(ar[q][2], ai[q][2], d2, w);
        }
        tw += step; if (tw >= NN) tw -= NN;
    }
    cplx w1 = W[j], w2 = W[2*j];
    __syncthreads();
    int k0 = j, k1 = j + 16, k2 = j + 32;
    if (shift) { k0 = (k0+24)%NN; k1 = (k1+24)%NN; k2 = (k2+24)%NN; }
#pragma unroll
    for (int q = 0; q < 3; ++q) {
        cplx X0, X1, X2;
        radix3_combine(ar[q][0],ai[q][0],ar[q][1],ai[q][1],ar[q][2],ai[q][2],w1,w2,X0,X1,X2);
        S[3*rg+q][k0] = X0; S[3*rg+q][k1] = X1; S[3*rg+q][k2] = X2;
    }
    __syncthreads();
}

// column DFT (first index), shifted, with DIRECT global store:
// out[k*rstride + col], k < rlimit, values scaled by `scale`. No trailing barrier.
__device__ __forceinline__ void dft_cols_g(cplx (*S)[NP], const cplx* W, int t,
                                           cplx* __restrict__ out, int rstride,
                                           int rlimit, float scale) {
    const int zg = t & 15;
    const int j  = t >> 4;
    float ar[3][3], ai[3][3];
#pragma unroll
    for (int zi = 0; zi < 3; ++zi)
#pragma unroll
        for (int r = 0; r < 3; ++r) { ar[zi][r] = 0.f; ai[zi][r] = 0.f; }
    const int step = 3 * j;
    int tw = 0;
#pragma unroll 4
    for (int n1 = 0; n1 < 16; ++n1) {
        cplx w = W[tw];
#pragma unroll
        for (int r = 0; r < 3; ++r) {
            const cplx* row = S[3*n1 + r];
            cplx d0 = row[3*zg+0], d1 = row[3*zg+1], d2 = row[3*zg+2];
            CMAC(ar[0][r], ai[0][r], d0, w);
            CMAC(ar[1][r], ai[1][r], d1, w);
            CMAC(ar[2][r], ai[2][r], d2, w);
        }
        tw += step; if (tw >= NN) tw -= NN;
    }
    cplx w1 = W[j], w2 = W[2*j];
    int k0 = j + 24;            // (j+24)%48, j<16
    int k1 = j + 40; if (k1 >= NN) k1 -= NN;
    int k2 = j + 8;
#pragma unroll
    for (int zi = 0; zi < 3; ++zi) {
        cplx X0, X1, X2;
        radix3_combine(ar[zi][0],ai[zi][0],ar[zi][1],ai[zi][1],ar[zi][2],ai[zi][2],w1,w2,X0,X1,X2);
        int c = 3*zg + zi;
        if (k0 < rlimit) out[(size_t)k0*rstride + c] = make_float2(X0.x*scale, X0.y*scale);
        if (k1 < rlimit) out[(size_t)k1*rstride + c] = make_float2(X1.x*scale, X1.y*scale);
        if (k2 < rlimit) out[(size_t)k2*rstride + c] = make_float2(X2.x*scale, X2.y*scale);
    }
}

// ---------- float4 (dual complex) radix-3 DFT helpers (kAB) ----------
__device__ __forceinline__ void dft_rows4(float4 (*S)[NP], const cplx* W, int t) {
    const int rg = t >> 4;
    const int j  = t & 15;
    float4 acc[3][3];
#pragma unroll
    for (int q = 0; q < 3; ++q)
#pragma unroll
        for (int r = 0; r < 3; ++r) acc[q][r] = make_float4(0.f,0.f,0.f,0.f);
    const int step = 3 * j;
    int tw = 0;
    const float4* r0 = S[3*rg + 0];
    const float4* r1 = S[3*rg + 1];
    const float4* r2 = S[3*rg + 2];
#pragma unroll 4
    for (int n1 = 0; n1 < 16; ++n1) {
        cplx w = W[tw];
        float4 d00 = r0[3*n1+0], d01 = r0[3*n1+1], d02 = r0[3*n1+2];
        float4 d10 = r1[3*n1+0], d11 = r1[3*n1+1], d12 = r1[3*n1+2];
        float4 d20 = r2[3*n1+0], d21 = r2[3*n1+1], d22 = r2[3*n1+2];
        CMAC4(acc[0][0], d00, w); CMAC4(acc[0][1], d01, w); CMAC4(acc[0][2], d02, w);
        CMAC4(acc[1][0], d10, w); CMAC4(acc[1][1], d11, w); CMAC4(acc[1][2], d12, w);
        CMAC4(acc[2][0], d20, w); CMAC4(acc[2][1], d21, w); CMAC4(acc[2][2], d22, w);
        tw += step; if (tw >= NN) tw -= NN;
    }
    cplx w1 = W[j], w2 = W[2*j];
    __syncthreads();
#pragma unroll
    for (int q = 0; q < 3; ++q) {
        float4 X0, X1, X2;
        radix3_combine4(acc[q][0], acc[q][1], acc[q][2], w1, w2, X0, X1, X2);
        S[3*rg+q][j] = X0; S[3*rg+q][j+16] = X1; S[3*rg+q][j+32] = X2;
    }
    __syncthreads();
}

// column DFT (first index), no shift, DIRECT global store: out[k*NN + col].
__device__ __forceinline__ void dft_cols4_g(float4 (*S)[NP], const cplx* W, int t,
                                            float4* __restrict__ out) {
    const int zg = t & 15;
    const int j  = t >> 4;
    float4 acc[3][3];   // [zi][r]
#pragma unroll
    for (int zi = 0; zi < 3; ++zi)
#pragma unroll
        for (int r = 0; r < 3; ++r) acc[zi][r] = make_float4(0.f,0.f,0.f,0.f);
    const int step = 3 * j;
    int tw = 0;
#pragma unroll 4
    for (int n1 = 0; n1 < 16; ++n1) {
        cplx w = W[tw];
#pragma unroll
        for (int r = 0; r < 3; ++r) {
            const float4* row = S[3*n1 + r];
            float4 d0 = row[3*zg+0], d1 = row[3*zg+1], d2 = row[3*zg+2];
            CMAC4(acc[0][r], d0, w);
            CMAC4(acc[1][r], d1, w);
            CMAC4(acc[2][r], d2, w);
        }
        tw += step; if (tw >= NN) tw -= NN;
    }
    cplx w1 = W[j], w2 = W[2*j];
#pragma unroll
    for (int zi = 0; zi < 3; ++zi) {
        float4 X0, X1, X2;
        radix3_combine4(acc[zi][0], acc[zi][1], acc[zi][2], w1, w2, X0, X1, X2);
        int c = 3*zg + zi;
        out[(size_t)(j     ) * NN + c] = X0;
        out[(size_t)(j + 16) * NN + c] = X1;
        out[(size_t)(j + 32) * NN + c] = X2;
    }
}

// f (real) -> DFT z, DFT y (both shifted), direct store
__global__ __launch_bounds__(256)
void kA_f(const float* __restrict__ f, cplx* __restrict__ out) {
    __shared__ cplx S[NN][NP];
    __shared__ cplx W[NN];
    const int x = blockIdx.x, b = blockIdx.y, t = threadIdx.x;
    const float* src = f + (size_t)b * N3 + (size_t)x * N2;
    for (int i = t; i < N2; i += 256) S[i / NN][i % NN] = make_float2(src[i], 0.f);
    twinit(W, t);
    __syncthreads();
    dft_rows(S, W, t, 1);
    cplx* dst = out + (size_t)b * N3 + (size_t)x * N2;
    dft_cols_g(S, W, t, dst, NN, NN, 1.f);
}

// finalize f_spec: DFT x (shifted), * 1/N3; direct store of ONLY the
// Hermitian half (k = 0..24) into compact spec_h[b][k][y][z].
__global__ __launch_bounds__(256)
void kB_f(const cplx* __restrict__ vol, cplx* __restrict__ outh) {
    __shared__ cplx S[NN][NP];
    __shared__ cplx W[NN];
    const int y = blockIdx.x, b = blockIdx.y, t = threadIdx.x;
    const cplx* base = vol + (size_t)b * N3 + (size_t)y * NN;
    for (int i = t; i < N2; i += 256) { int xr = i / NN, z = i % NN; S[xr][z] = base[(size_t)xr * N2 + z]; }
    twinit(W, t);
    __syncthreads();
    cplx* dst = outh + (size_t)b * NHN2 + (size_t)y * NN;
    dft_cols_g(S, W, t, dst, N2, NH, 1.f / (float)N3);
}

// Fused A-pass: va = F2(spec*phi), vb = F2(spec*psi) as dual-complex float4,
// direct store. blockIdx.z = lt; ti = t0+lt; ti==NT -> fl pair (phipsi, 1).
__global__ __launch_bounds__(256)
void kAB(const cplx* __restrict__ spec,
         const float* __restrict__ phi, const float* __restrict__ psi,
         const float* __restrict__ phipsi,
         float4* __restrict__ vab, int t0) {
    __shared__ float4 S[NN][NP];
    __shared__ cplx W[NN];
    const int ix = blockIdx.x, b = blockIdx.y, lt = blockIdx.z, t = threadIdx.x;
    const int ti = t0 + lt;
    const cplx* src = spec + (size_t)b * NHN2 + (size_t)ix * N2;
    const float* mp;
    const float* mq;
    if (ti < NT) { mp = phi + (size_t)ti * N3 + (size_t)ix * N2; mq = psi + (size_t)ti * N3 + (size_t)ix * N2; }
    else         { mp = phipsi + (size_t)ix * N2;               mq = (const float*)nullptr; }
    for (int i = t; i < N2; i += 256) {
        cplx v = src[i];
        float p = mp[i];
        float q = mq ? mq[i] : 1.f;
        S[i / NN][i % NN] = make_float4(v.x * p, v.y * p, v.x * q, v.y * q);
    }
    twinit(W, t);
    __syncthreads();
    dft_rows4(S, W, t);
    float4* out = vab + ((size_t)(lt * NB + b) * NH + ix) * N2;
    dft_cols4_g(S, W, t, out);
}

// Real-valued x-DFT via Hermitian symmetry + product + t-accumulate.
// Ah[j] = A[0] + (-1)^j A[24] + 2*sum_{n=1}^{23} Re(A[n] W48^{nj}).
// Register-prefetched tile staging (round-7, kept).
__global__ __launch_bounds__(256)
void kB_all(const float4* __restrict__ vab,
            float* __restrict__ out, const float* __restrict__ kn,
            const int* __restrict__ Mv, int t0, int cn) {
    __shared__ float4 SAB[NH][NN];   // 1200 float4, linear (2-way bank alias = free)
    __shared__ cplx W[NN];
    const int y = blockIdx.x, b = blockIdx.y, s = blockIdx.z, t = threadIdx.x;
    twinit(W, t);
    const int zg = t & 15, jg = t >> 4;
    const int i4 = 1024 + t;                 // 5th staged element index
    float4* SF = (float4*)SAB;
    float qr[3][3];
#pragma unroll
    for (int m = 0; m < 3; ++m)
#pragma unroll
        for (int zi = 0; zi < 3; ++zi) qr[m][zi] = 0.f;

    float4 R0, R1, R2, R3, R4;
    {   // prologue: stage first tile into regs
        const float4* base = vab + (size_t)(s * NB + b) * NH * N2 + (size_t)y * NN;
        R0 = base[(size_t)((t          ) / NN) * N2 + ((t          ) % NN)];
        R1 = base[(size_t)((t +  256   ) / NN) * N2 + ((t +  256   ) % NN)];
        R2 = base[(size_t)((t +  512   ) / NN) * N2 + ((t +  512   ) % NN)];
        R3 = base[(size_t)((t +  768   ) / NN) * N2 + ((t +  768   ) % NN)];
        if (i4 < NH * NN) R4 = base[(size_t)(i4 / NN) * N2 + (i4 % NN)];
    }

    for (int lt = s; lt < cn; lt += NSL) {
        const int ti = t0 + lt;
        SF[t]        = R0;
        SF[t +  256] = R1;
        SF[t +  512] = R2;
        SF[t +  768] = R3;
        if (i4 < NH * NN) SF[i4] = R4;
        __syncthreads();
        if (lt + NSL < cn) {
            const float4* base = vab + (size_t)((lt + NSL) * NB + b) * NH * N2 + (size_t)y * NN;
            R0 = base[(size_t)((t          ) / NN) * N2 + ((t          ) % NN)];
            R1 = base[(size_t)((t +  256   ) / NN) * N2 + ((t +  256   ) % NN)];
            R2 = base[(size_t)((t +  512   ) / NN) * N2 + ((t +  512   ) % NN)];
            R3 = base[(size_t)((t +  768   ) / NN) * N2 + ((t +  768   ) % NN)];
            if (i4 < NH * NN) R4 = base[(size_t)(i4 / NN) * N2 + (i4 % NN)];
        }
        float sa[3][3], sb[3][3];   // [m][zi]
#pragma unroll
        for (int m = 0; m < 3; ++m)
#pragma unroll
            for (int zi = 0; zi < 3; ++zi) { sa[m][zi] = 0.f; sb[m][zi] = 0.f; }
        int m0 = jg, m1 = jg + 16, m2 = jg + 32;
        const int s0 = jg, s1 = jg + 16, s2 = jg + 32;
        for (int n = 1; n <= 23; ++n) {
            cplx w0 = W[m0], w1 = W[m1], w2 = W[m2];
#pragma unroll
            for (int zi = 0; zi < 3; ++zi) {
                float4 d = SAB[n][3 * zg + zi];
                sa[0][zi] = fmaf(d.x, w0.x, sa[0][zi]); sa[0][zi] = fmaf(-d.y, w0.y, sa[0][zi]);
                sa[1][zi] = fmaf(d.x, w1.x, sa[1][zi]); sa[1][zi] = fmaf(-d.y, w1.y, sa[1][zi]);
                sa[2][zi] = fmaf(d.x, w2.x, sa[2][zi]); sa[2][zi] = fmaf(-d.y, w2.y, sa[2][zi]);
                sb[0][zi] = fmaf(d.z, w0.x, sb[0][zi]); sb[0][zi] = fmaf(-d.w, w0.y, sb[0][zi]);
                sb[1][zi] = fmaf(d.z, w1.x, sb[1][zi]); sb[1][zi] = fmaf(-d.w, w1.y, sb[1][zi]);
                sb[2][zi] = fmaf(d.z, w2.x, sb[2][zi]); sb[2][zi] = fmaf(-d.w, w2.y, sb[2][zi]);
            }
            m0 += s0; if (m0 >= NN) m0 -= NN;
            m1 += s1; if (m1 >= NN) m1 -= NN;
            m2 += s2; if (m2 >= NN) m2 -= NN;
        }
        const float sgn = (jg & 1) ? -1.f : 1.f;   // j = jg+16m, parity(j)=parity(jg)
        const float wgt = (ti == NT) ? -1.f : 1.f;
#pragma unroll
        for (int zi = 0; zi < 3; ++zi) {
            float4 e0  = SAB[0][3 * zg + zi];
            float4 e24 = SAB[24][3 * zg + zi];
            float basea = e0.x + sgn * e24.x;
            float baseb = e0.z + sgn * e24.z;
#pragma unroll
            for (int m = 0; m < 3; ++m) {
                float Ah = basea + 2.f * sa[m][zi];
                float Bh = baseb + 2.f * sb[m][zi];
                qr[m][zi] += wgt * Ah * Bh;
            }
        }
        __syncthreads();   // protect SAB before next iteration's ds_write
    }
    float mf = (float)(Mv[0] * Mv[0]);
    float scale = 4.f * 3.14159265358979323846f * 3.14159265358979323846f / (kn[0] * mf);
#pragma unroll
    for (int m = 0; m < 3; ++m) {
        int j = jg + 16 * m;
#pragma unroll
        for (int zi = 0; zi < 3; ++zi) {
            int z = 3 * zg + zi;
            size_t idx = (size_t)b * N3 + (size_t)j * N2 + (size_t)y * NN + z;
            atomicAdd(&out[idx], scale * qr[m][zi]);
        }
    }
}

extern "C" void kernel_launch(void* const* d_in, const int* in_sizes, int n_in,
                              void* d_out, int out_size, void* d_ws, size_t ws_size,
                              hipStream_t stream) {
    const float* f      = (const float*)d_in[0];
    const float* kn     = (const float*)d_in[1];
    const float* phi    = (const float*)d_in[2];
    const float* psi    = (const float*)d_in[3];
    const float* phipsi = (const float*)d_in[4];
    const int*   Mv     = (const int*)d_in[5];
    float* out = (float*)d_out;

    char* w = (char*)d_ws;
    const size_t fspecB = (size_t)NB * N3 * sizeof(cplx);            // 7,077,888
    const size_t spechB = (size_t)NB * NHN2 * sizeof(cplx);          // 3,686,400
    const size_t perTB  = (size_t)NB * NH * N2 * sizeof(float4);     // 7,372,800 per t
    cplx* fspec = (cplx*)w;
    cplx* spech = (cplx*)(w + fspecB);
    char* pool  = w + fspecB + spechB;

    const int NTOT = NT + 1;   // 20 fg terms + 1 fl term
    size_t head = fspecB + spechB;
    size_t avail = (ws_size > head) ? (ws_size - head) : 0;
    int chunk = (int)(avail / perTB);
    if (chunk < 1)    chunk = 1;
    if (chunk > NTOT) chunk = NTOT;
    float4* vab = (float4*)pool;

    hipMemsetAsync(out, 0, (size_t)NB * N3 * sizeof(float), stream);

    kA_f<<<dim3(NN, NB), 256, 0, stream>>>(f, fspec);
    kB_f<<<dim3(NN, NB), 256, 0, stream>>>(fspec, spech);

    for (int t0 = 0; t0 < NTOT; t0 += chunk) {
        int cn = (t0 + chunk <= NTOT) ? chunk : (NTOT - t0);
        kAB<<<dim3(NH, NB, cn), 256, 0, stream>>>(spech, phi, psi, phipsi, vab, t0);
        int zb = (cn < NSL) ? cn : NSL;
        kB_all<<<dim3(NN, NB, zb), 256, 0, stream>>>(vab, out, kn, Mv, t0, cn);
    }
}

// Round 12
// 267.105 us; speedup vs baseline: 1.0488x; 1.0117x over previous
//
#include <hip/hip_runtime.h>
#include <math.h>

#define NN 48
#define NP 49
#define N2 2304
#define N3 110592
#define NB 8
#define NT 20
#define NH 25          // Hermitian half: slabs 0..24
#define NHN2 57600     // NH * N2
#define NSL 7          // t-slices in kB_all

typedef float2 cplx;

// acc += d * w  (complex MAC, 4 FMA)
#define CMAC(AR, AI, D, Wv)                                        \
    AR = fmaf((D).x, (Wv).x, AR); AR = fmaf(-(D).y, (Wv).y, AR);   \
    AI = fmaf((D).x, (Wv).y, AI); AI = fmaf((D).y, (Wv).x, AI);

// dual complex MAC on float4 (A in .xy, B in .zw), 8 FMA, one twiddle
#define CMAC4(AC, D, Wv)                                             \
    (AC).x = fmaf((D).x, (Wv).x, (AC).x); (AC).x = fmaf(-(D).y, (Wv).y, (AC).x); \
    (AC).y = fmaf((D).x, (Wv).y, (AC).y); (AC).y = fmaf((D).y, (Wv).x, (AC).y); \
    (AC).z = fmaf((D).z, (Wv).x, (AC).z); (AC).z = fmaf(-(D).w, (Wv).y, (AC).z); \
    (AC).w = fmaf((D).z, (Wv).y, (AC).w); (AC).w = fmaf((D).w, (Wv).x, (AC).w);

__device__ __forceinline__ void twinit(cplx* W, int t) {
    if (t < NN) {
        float ang = -6.28318530717958647692f * (float)t / (float)NN;
        float s, c;
        sincosf(ang, &s, &c);
        W[t] = make_float2(c, s);
    }
}

// radix-3 combine (complex): X[j+16m] = sum_r w3^(rm) * (S_r * W48^(rj))
__device__ __forceinline__ void radix3_combine(
    float s0r, float s0i, float s1r, float s1i, float s2r, float s2i,
    cplx w1, cplx w2, cplx& X0, cplx& X1, cplx& X2)
{
    float y1r = s1r*w1.x - s1i*w1.y, y1i = s1r*w1.y + s1i*w1.x;
    float y2r = s2r*w2.x - s2i*w2.y, y2i = s2r*w2.y + s2i*w2.x;
    float ar = y1r + y2r, ai = y1i + y2i;
    float br = y1r - y2r, bi = y1i - y2i;
    X0 = make_float2(s0r + ar, s0i + ai);
    float mr = s0r - 0.5f*ar, mi = s0i - 0.5f*ai;
    const float h = 0.86602540378443864676f;
    X1 = make_float2(mr + h*bi, mi - h*br);
    X2 = make_float2(mr - h*bi, mi + h*br);
}

// radix-3 combine on dual-complex float4
__device__ __forceinline__ void radix3_combine4(
    float4 s0, float4 s1, float4 s2, cplx w1, cplx w2,
    float4& X0, float4& X1, float4& X2)
{
    cplx a0, a1, a2, b0, b1, b2;
    radix3_combine(s0.x, s0.y, s1.x, s1.y, s2.x, s2.y, w1, w2, a0, a1, a2);
    radix3_combine(s0.z, s0.w, s1.z, s1.w, s2.z, s2.w, w1, w2, b0, b1, b2);
    X0 = make_float4(a0.x, a0.y, b0.x, b0.y);
    X1 = make_float4(a1.x, a1.y, b1.x, b1.y);
    X2 = make_float4(a2.x, a2.y, b2.x, b2.y);
}

// ---------- float2 (cplx) radix-3 DFT helpers ----------
__device__ __forceinline__ void dft_rows(cplx (*S)[NP], const cplx* W, int t, int shift) {
    const int rg = t >> 4;
    const int j  = t & 15;
    float ar[3][3], ai[3][3];
#pragma unroll
    for (int q = 0; q < 3; ++q)
#pragma unroll
        for (int r = 0; r < 3; ++r) { ar[q][r] = 0.f; ai[q][r] = 0.f; }
    const int step = 3 * j;
    int tw = 0;
#pragma unroll 4
    for (int n1 = 0; n1 < 16; ++n1) {
        cplx w = W[tw];
#pragma unroll
        for (int q = 0; q < 3; ++q) {
            const cplx* row = S[3*rg + q];
            cplx d0 = row[3*n1+0], d1 = row[3*n1+1], d2 = row[3*n1+2];
            CMAC(ar[q][0], ai[q][0], d0, w);
            CMAC(ar[q][1], ai[q][1], d1, w);
            CMAC(ar[q][2], ai[q][2], d2, w);
        }
        tw += step; if (tw >= NN) tw -= NN;
    }
    cplx w1 = W[j], w2 = W[2*j];
    __syncthreads();
    int k0 = j, k1 = j + 16, k2 = j + 32;
    if (shift) { k0 = (k0+24)%NN; k1 = (k1+24)%NN; k2 = (k2+24)%NN; }
#pragma unroll
    for (int q = 0; q < 3; ++q) {
        cplx X0, X1, X2;
        radix3_combine(ar[q][0],ai[q][0],ar[q][1],ai[q][1],ar[q][2],ai[q][2],w1,w2,X0,X1,X2);
        S[3*rg+q][k0] = X0; S[3*rg+q][k1] = X1; S[3*rg+q][k2] = X2;
    }
    __syncthreads();
}

// column DFT (first index), shifted, with DIRECT global store:
// out[k*rstride + col], k < rlimit, values scaled by `scale`. No trailing barrier.
__device__ __forceinline__ void dft_cols_g(cplx (*S)[NP], const cplx* W, int t,
                                           cplx* __restrict__ out, int rstride,
                                           int rlimit, float scale) {
    const int zg = t & 15;
    const int j  = t >> 4;
    float ar[3][3], ai[3][3];
#pragma unroll
    for (int zi = 0; zi < 3; ++zi)
#pragma unroll
        for (int r = 0; r < 3; ++r) { ar[zi][r] = 0.f; ai[zi][r] = 0.f; }
    const int step = 3 * j;
    int tw = 0;
#pragma unroll 4
    for (int n1 = 0; n1 < 16; ++n1) {
        cplx w = W[tw];
#pragma unroll
        for (int r = 0; r < 3; ++r) {
            const cplx* row = S[3*n1 + r];
            cplx d0 = row[3*zg+0], d1 = row[3*zg+1], d2 = row[3*zg+2];
            CMAC(ar[0][r], ai[0][r], d0, w);
            CMAC(ar[1][r], ai[1][r], d1, w);
            CMAC(ar[2][r], ai[2][r], d2, w);
        }
        tw += step; if (tw >= NN) tw -= NN;
    }
    cplx w1 = W[j], w2 = W[2*j];
    int k0 = j + 24;            // (j+24)%48, j<16
    int k1 = j + 40; if (k1 >= NN) k1 -= NN;
    int k2 = j + 8;
#pragma unroll
    for (int zi = 0; zi < 3; ++zi) {
        cplx X0, X1, X2;
        radix3_combine(ar[zi][0],ai[zi][0],ar[zi][1],ai[zi][1],ar[zi][2],ai[zi][2],w1,w2,X0,X1,X2);
        int c = 3*zg + zi;
        if (k0 < rlimit) out[(size_t)k0*rstride + c] = make_float2(X0.x*scale, X0.y*scale);
        if (k1 < rlimit) out[(size_t)k1*rstride + c] = make_float2(X1.x*scale, X1.y*scale);
        if (k2 < rlimit) out[(size_t)k2*rstride + c] = make_float2(X2.x*scale, X2.y*scale);
    }
}

// ---------- float4 (dual complex) radix-3 DFT helpers (kAB) ----------
__device__ __forceinline__ void dft_rows4(float4 (*S)[NP], const cplx* W, int t) {
    const int rg = t >> 4;
    const int j  = t & 15;
    float4 acc[3][3];
#pragma unroll
    for (int q = 0; q < 3; ++q)
#pragma unroll
        for (int r = 0; r < 3; ++r) acc[q][r] = make_float4(0.f,0.f,0.f,0.f);
    const int step = 3 * j;
    int tw = 0;
    const float4* r0 = S[3*rg + 0];
    const float4* r1 = S[3*rg + 1];
    const float4* r2 = S[3*rg + 2];
#pragma unroll 4
    for (int n1 = 0; n1 < 16; ++n1) {
        cplx w = W[tw];
        float4 d00 = r0[3*n1+0], d01 = r0[3*n1+1], d02 = r0[3*n1+2];
        float4 d10 = r1[3*n1+0], d11 = r1[3*n1+1], d12 = r1[3*n1+2];
        float4 d20 = r2[3*n1+0], d21 = r2[3*n1+1], d22 = r2[3*n1+2];
        CMAC4(acc[0][0], d00, w); CMAC4(acc[0][1], d01, w); CMAC4(acc[0][2], d02, w);
        CMAC4(acc[1][0], d10, w); CMAC4(acc[1][1], d11, w); CMAC4(acc[1][2], d12, w);
        CMAC4(acc[2][0], d20, w); CMAC4(acc[2][1], d21, w); CMAC4(acc[2][2], d22, w);
        tw += step; if (tw >= NN) tw -= NN;
    }
    cplx w1 = W[j], w2 = W[2*j];
    __syncthreads();
#pragma unroll
    for (int q = 0; q < 3; ++q) {
        float4 X0, X1, X2;
        radix3_combine4(acc[q][0], acc[q][1], acc[q][2], w1, w2, X0, X1, X2);
        S[3*rg+q][j] = X0; S[3*rg+q][j+16] = X1; S[3*rg+q][j+32] = X2;
    }
    __syncthreads();
}

__device__ __forceinline__ void dft_cols4(float4 (*S)[NP], const cplx* W, int t) {
    const int zg = t & 15;
    const int j  = t >> 4;
    float4 acc[3][3];   // [zi][r]
#pragma unroll
    for (int zi = 0; zi < 3; ++zi)
#pragma unroll
        for (int r = 0; r < 3; ++r) acc[zi][r] = make_float4(0.f,0.f,0.f,0.f);
    const int step = 3 * j;
    int tw = 0;
#pragma unroll 4
    for (int n1 = 0; n1 < 16; ++n1) {
        cplx w = W[tw];
#pragma unroll
        for (int r = 0; r < 3; ++r) {
            const float4* row = S[3*n1 + r];
            float4 d0 = row[3*zg+0], d1 = row[3*zg+1], d2 = row[3*zg+2];
            CMAC4(acc[0][r], d0, w);
            CMAC4(acc[1][r], d1, w);
            CMAC4(acc[2][r], d2, w);
        }
        tw += step; if (tw >= NN) tw -= NN;
    }
    cplx w1 = W[j], w2 = W[2*j];
    __syncthreads();
#pragma unroll
    for (int zi = 0; zi < 3; ++zi) {
        float4 X0, X1, X2;
        radix3_combine4(acc[zi][0], acc[zi][1], acc[zi][2], w1, w2, X0, X1, X2);
        S[j][3*zg+zi] = X0; S[j+16][3*zg+zi] = X1; S[j+32][3*zg+zi] = X2;
    }
    __syncthreads();
}

// f (real) -> DFT z, DFT y (both shifted), direct store
__global__ __launch_bounds__(256)
void kA_f(const float* __restrict__ f, cplx* __restrict__ out) {
    __shared__ cplx S[NN][NP];
    __shared__ cplx W[NN];
    const int x = blockIdx.x, b = blockIdx.y, t = threadIdx.x;
    const float* src = f + (size_t)b * N3 + (size_t)x * N2;
    for (int i = t; i < N2; i += 256) S[i / NN][i % NN] = make_float2(src[i], 0.f);
    twinit(W, t);
    __syncthreads();
    dft_rows(S, W, t, 1);
    cplx* dst = out + (size_t)b * N3 + (size_t)x * N2;
    dft_cols_g(S, W, t, dst, NN, NN, 1.f);
}

// finalize f_spec: DFT x (shifted), * 1/N3; direct store of ONLY the
// Hermitian half (k = 0..24) into compact spec_h[b][k][y][z].
__global__ __launch_bounds__(256)
void kB_f(const cplx* __restrict__ vol, cplx* __restrict__ outh) {
    __shared__ cplx S[NN][NP];
    __shared__ cplx W[NN];
    const int y = blockIdx.x, b = blockIdx.y, t = threadIdx.x;
    const cplx* base = vol + (size_t)b * N3 + (size_t)y * NN;
    for (int i = t; i < N2; i += 256) { int xr = i / NN, z = i % NN; S[xr][z] = base[(size_t)xr * N2 + z]; }
    twinit(W, t);
    __syncthreads();
    cplx* dst = outh + (size_t)b * NHN2 + (size_t)y * NN;
    dft_cols_g(S, W, t, dst, N2, NH, 1.f / (float)N3);
}

// Fused A-pass: va = F2(spec*phi), vb = F2(spec*psi) as dual-complex float4.
// Round-10 epilogue restored: LDS write-back + coalesced linear copy.
// blockIdx.z = lt; ti = t0+lt; ti==NT -> fl pair (phipsi, identity).
__global__ __launch_bounds__(256)
void kAB(const cplx* __restrict__ spec,
         const float* __restrict__ phi, const float* __restrict__ psi,
         const float* __restrict__ phipsi,
         float4* __restrict__ vab, int t0) {
    __shared__ float4 S[NN][NP];
    __shared__ cplx W[NN];
    const int ix = blockIdx.x, b = blockIdx.y, lt = blockIdx.z, t = threadIdx.x;
    const int ti = t0 + lt;
    const cplx* src = spec + (size_t)b * NHN2 + (size_t)ix * N2;
    const float* mp;
    const float* mq;
    if (ti < NT) { mp = phi + (size_t)ti * N3 + (size_t)ix * N2; mq = psi + (size_t)ti * N3 + (size_t)ix * N2; }
    else         { mp = phipsi + (size_t)ix * N2;               mq = (const float*)nullptr; }
    for (int i = t; i < N2; i += 256) {
        cplx v = src[i];
        float p = mp[i];
        float q = mq ? mq[i] : 1.f;
        S[i / NN][i % NN] = make_float4(v.x * p, v.y * p, v.x * q, v.y * q);
    }
    twinit(W, t);
    __syncthreads();
    dft_rows4(S, W, t);
    dft_cols4(S, W, t);
    float4* out = vab + ((size_t)(lt * NB + b) * NH + ix) * N2;
    for (int i = t; i < N2; i += 256) out[i] = S[i / NN][i % NN];
}

// Real-valued x-DFT via Hermitian symmetry + product + t-accumulate.
// Ah[j] = A[0] + (-1)^j A[24] + 2*sum_{n=1}^{23} Re(A[n] W48^{nj}).
// Register-prefetched tile staging (round-7, kept).
__global__ __launch_bounds__(256)
void kB_all(const float4* __restrict__ vab,
            float* __restrict__ out, const float* __restrict__ kn,
            const int* __restrict__ Mv, int t0, int cn) {
    __shared__ float4 SAB[NH][NN];   // 1200 float4, linear (2-way bank alias = free)
    __shared__ cplx W[NN];
    const int y = blockIdx.x, b = blockIdx.y, s = blockIdx.z, t = threadIdx.x;
    twinit(W, t);
    const int zg = t & 15, jg = t >> 4;
    const int i4 = 1024 + t;                 // 5th staged element index
    float4* SF = (float4*)SAB;
    float qr[3][3];
#pragma unroll
    for (int m = 0; m < 3; ++m)
#pragma unroll
        for (int zi = 0; zi < 3; ++zi) qr[m][zi] = 0.f;

    float4 R0, R1, R2, R3, R4;
    {   // prologue: stage first tile into regs
        const float4* base = vab + (size_t)(s * NB + b) * NH * N2 + (size_t)y * NN;
        R0 = base[(size_t)((t          ) / NN) * N2 + ((t          ) % NN)];
        R1 = base[(size_t)((t +  256   ) / NN) * N2 + ((t +  256   ) % NN)];
        R2 = base[(size_t)((t +  512   ) / NN) * N2 + ((t +  512   ) % NN)];
        R3 = base[(size_t)((t +  768   ) / NN) * N2 + ((t +  768   ) % NN)];
        if (i4 < NH * NN) R4 = base[(size_t)(i4 / NN) * N2 + (i4 % NN)];
    }

    for (int lt = s; lt < cn; lt += NSL) {
        const int ti = t0 + lt;
        SF[t]        = R0;
        SF[t +  256] = R1;
        SF[t +  512] = R2;
        SF[t +  768] = R3;
        if (i4 < NH * NN) SF[i4] = R4;
        __syncthreads();
        if (lt + NSL < cn) {
            const float4* base = vab + (size_t)((lt + NSL) * NB + b) * NH * N2 + (size_t)y * NN;
            R0 = base[(size_t)((t          ) / NN) * N2 + ((t          ) % NN)];
            R1 = base[(size_t)((t +  256   ) / NN) * N2 + ((t +  256   ) % NN)];
            R2 = base[(size_t)((t +  512   ) / NN) * N2 + ((t +  512   ) % NN)];
            R3 = base[(size_t)((t +  768   ) / NN) * N2 + ((t +  768   ) % NN)];
            if (i4 < NH * NN) R4 = base[(size_t)(i4 / NN) * N2 + (i4 % NN)];
        }
        float sa[3][3], sb[3][3];   // [m][zi]
#pragma unroll
        for (int m = 0; m < 3; ++m)
#pragma unroll
            for (int zi = 0; zi < 3; ++zi) { sa[m][zi] = 0.f; sb[m][zi] = 0.f; }
        int m0 = jg, m1 = jg + 16, m2 = jg + 32;
        const int s0 = jg, s1 = jg + 16, s2 = jg + 32;
        for (int n = 1; n <= 23; ++n) {
            cplx w0 = W[m0], w1 = W[m1], w2 = W[m2];
#pragma unroll
            for (int zi = 0; zi < 3; ++zi) {
                float4 d = SAB[n][3 * zg + zi];
                sa[0][zi] = fmaf(d.x, w0.x, sa[0][zi]); sa[0][zi] = fmaf(-d.y, w0.y, sa[0][zi]);
                sa[1][zi] = fmaf(d.x, w1.x, sa[1][zi]); sa[1][zi] = fmaf(-d.y, w1.y, sa[1][zi]);
                sa[2][zi] = fmaf(d.x, w2.x, sa[2][zi]); sa[2][zi] = fmaf(-d.y, w2.y, sa[2][zi]);
                sb[0][zi] = fmaf(d.z, w0.x, sb[0][zi]); sb[0][zi] = fmaf(-d.w, w0.y, sb[0][zi]);
                sb[1][zi] = fmaf(d.z, w1.x, sb[1][zi]); sb[1][zi] = fmaf(-d.w, w1.y, sb[1][zi]);
                sb[2][zi] = fmaf(d.z, w2.x, sb[2][zi]); sb[2][zi] = fmaf(-d.w, w2.y, sb[2][zi]);
            }
            m0 += s0; if (m0 >= NN) m0 -= NN;
            m1 += s1; if (m1 >= NN) m1 -= NN;
            m2 += s2; if (m2 >= NN) m2 -= NN;
        }
        const float sgn = (jg & 1) ? -1.f : 1.f;   // j = jg+16m, parity(j)=parity(jg)
        const float wgt = (ti == NT) ? -1.f : 1.f;
#pragma unroll
        for (int zi = 0; zi < 3; ++zi) {
            float4 e0  = SAB[0][3 * zg + zi];
            float4 e24 = SAB[24][3 * zg + zi];
            float basea = e0.x + sgn * e24.x;
            float baseb = e0.z + sgn * e24.z;
#pragma unroll
            for (int m = 0; m < 3; ++m) {
                float Ah = basea + 2.f * sa[m][zi];
                float Bh = baseb + 2.f * sb[m][zi];
                qr[m][zi] += wgt * Ah * Bh;
            }
        }
        __syncthreads();   // protect SAB before next iteration's ds_write
    }
    float mf = (float)(Mv[0] * Mv[0]);
    float scale = 4.f * 3.14159265358979323846f * 3.14159265358979323846f / (kn[0] * mf);
#pragma unroll
    for (int m = 0; m < 3; ++m) {
        int j = jg + 16 * m;
#pragma unroll
        for (int zi = 0; zi < 3; ++zi) {
            int z = 3 * zg + zi;
            size_t idx = (size_t)b * N3 + (size_t)j * N2 + (size_t)y * NN + z;
            atomicAdd(&out[idx], scale * qr[m][zi]);
        }
    }
}

extern "C" void kernel_launch(void* const* d_in, const int* in_sizes, int n_in,
                              void* d_out, int out_size, void* d_ws, size_t ws_size,
                              hipStream_t stream) {
    const float* f      = (const float*)d_in[0];
    const float* kn     = (const float*)d_in[1];
    const float* phi    = (const float*)d_in[2];
    const float* psi    = (const float*)d_in[3];
    const float* phipsi = (const float*)d_in[4];
    const int*   Mv     = (const int*)d_in[5];
    float* out = (float*)d_out;

    char* w = (char*)d_ws;
    const size_t fspecB = (size_t)NB * N3 * sizeof(cplx);            // 7,077,888
    const size_t spechB = (size_t)NB * NHN2 * sizeof(cplx);          // 3,686,400
    const size_t perTB  = (size_t)NB * NH * N2 * sizeof(float4);     // 7,372,800 per t
    cplx* fspec = (cplx*)w;
    cplx* spech = (cplx*)(w + fspecB);
    char* pool  = w + fspecB + spechB;

    const int NTOT = NT + 1;   // 20 fg terms + 1 fl term
    size_t head = fspecB + spechB;
    size_t avail = (ws_size > head) ? (ws_size - head) : 0;
    int chunk = (int)(avail / perTB);
    if (chunk < 1)    chunk = 1;
    if (chunk > NTOT) chunk = NTOT;
    float4* vab = (float4*)pool;

    hipMemsetAsync(out, 0, (size_t)NB * N3 * sizeof(float), stream);

    kA_f<<<dim3(NN, NB), 256, 0, stream>>>(f, fspec);
    kB_f<<<dim3(NN, NB), 256, 0, stream>>>(fspec, spech);

    for (int t0 = 0; t0 < NTOT; t0 += chunk) {
        int cn = (t0 + chunk <= NTOT) ? chunk : (NTOT - t0);
        kAB<<<dim3(NH, NB, cn), 256, 0, stream>>>(spech, phi, psi, phipsi, vab, t0);
        int zb = (cn < NSL) ? cn : NSL;
        kB_all<<<dim3(NN, NB, zb), 256, 0, stream>>>(vab, out, kn, Mv, t0, cn);
    }
}

// Round 13
// 259.563 us; speedup vs baseline: 1.0793x; 1.0291x over previous
//
#include <hip/hip_runtime.h>
#include <math.h>

#define NN 48
#define NP 49
#define N2 2304
#define N3 110592
#define NB 8
#define NT 20
#define NH 25          // Hermitian half: slabs 0..24
#define NHN2 57600     // NH * N2
#define NSL 7          // t-slices in kB_all

typedef float2 cplx;

// acc += d * w  (complex MAC, 4 FMA)
#define CMAC(AR, AI, D, Wv)                                        \
    AR = fmaf((D).x, (Wv).x, AR); AR = fmaf(-(D).y, (Wv).y, AR);   \
    AI = fmaf((D).x, (Wv).y, AI); AI = fmaf((D).y, (Wv).x, AI);

// dual complex MAC on float4 (A in .xy, B in .zw), 8 FMA, one twiddle
#define CMAC4(AC, D, Wv)                                             \
    (AC).x = fmaf((D).x, (Wv).x, (AC).x); (AC).x = fmaf(-(D).y, (Wv).y, (AC).x); \
    (AC).y = fmaf((D).x, (Wv).y, (AC).y); (AC).y = fmaf((D).y, (Wv).x, (AC).y); \
    (AC).z = fmaf((D).z, (Wv).x, (AC).z); (AC).z = fmaf(-(D).w, (Wv).y, (AC).z); \
    (AC).w = fmaf((D).z, (Wv).y, (AC).w); (AC).w = fmaf((D).w, (Wv).x, (AC).w);

__device__ __forceinline__ void twinit(cplx* W, int t) {
    if (t < NN) {
        float ang = -6.28318530717958647692f * (float)t / (float)NN;
        float s, c;
        sincosf(ang, &s, &c);
        W[t] = make_float2(c, s);
    }
}

// radix-3 combine (complex): X[j+16m] = sum_r w3^(rm) * (S_r * W48^(rj))
__device__ __forceinline__ void radix3_combine(
    float s0r, float s0i, float s1r, float s1i, float s2r, float s2i,
    cplx w1, cplx w2, cplx& X0, cplx& X1, cplx& X2)
{
    float y1r = s1r*w1.x - s1i*w1.y, y1i = s1r*w1.y + s1i*w1.x;
    float y2r = s2r*w2.x - s2i*w2.y, y2i = s2r*w2.y + s2i*w2.x;
    float ar = y1r + y2r, ai = y1i + y2i;
    float br = y1r - y2r, bi = y1i - y2i;
    X0 = make_float2(s0r + ar, s0i + ai);
    float mr = s0r - 0.5f*ar, mi = s0i - 0.5f*ai;
    const float h = 0.86602540378443864676f;
    X1 = make_float2(mr + h*bi, mi - h*br);
    X2 = make_float2(mr - h*bi, mi + h*br);
}

// radix-3 combine on dual-complex float4
__device__ __forceinline__ void radix3_combine4(
    float4 s0, float4 s1, float4 s2, cplx w1, cplx w2,
    float4& X0, float4& X1, float4& X2)
{
    cplx a0, a1, a2, b0, b1, b2;
    radix3_combine(s0.x, s0.y, s1.x, s1.y, s2.x, s2.y, w1, w2, a0, a1, a2);
    radix3_combine(s0.z, s0.w, s1.z, s1.w, s2.z, s2.w, w1, w2, b0, b1, b2);
    X0 = make_float4(a0.x, a0.y, b0.x, b0.y);
    X1 = make_float4(a1.x, a1.y, b1.x, b1.y);
    X2 = make_float4(a2.x, a2.y, b2.x, b2.y);
}

// ---------- float2 (cplx) radix-3 DFT helpers ----------
// column DFT (first index, y), in-LDS, optional shift
__device__ __forceinline__ void dft_cols(cplx (*S)[NP], const cplx* W, int t, int shift) {
    const int zg = t & 15;
    const int j  = t >> 4;
    float ar[3][3], ai[3][3];
#pragma unroll
    for (int zi = 0; zi < 3; ++zi)
#pragma unroll
        for (int r = 0; r < 3; ++r) { ar[zi][r] = 0.f; ai[zi][r] = 0.f; }
    const int step = 3 * j;
    int tw = 0;
#pragma unroll 4
    for (int n1 = 0; n1 < 16; ++n1) {
        cplx w = W[tw];
#pragma unroll
        for (int r = 0; r < 3; ++r) {
            const cplx* row = S[3*n1 + r];
            cplx d0 = row[3*zg+0], d1 = row[3*zg+1], d2 = row[3*zg+2];
            CMAC(ar[0][r], ai[0][r], d0, w);
            CMAC(ar[1][r], ai[1][r], d1, w);
            CMAC(ar[2][r], ai[2][r], d2, w);
        }
        tw += step; if (tw >= NN) tw -= NN;
    }
    cplx w1 = W[j], w2 = W[2*j];
    __syncthreads();
    int k0 = j, k1 = j + 16, k2 = j + 32;
    if (shift) { k0 = (k0+24)%NN; k1 = (k1+24)%NN; k2 = (k2+24)%NN; }
#pragma unroll
    for (int zi = 0; zi < 3; ++zi) {
        cplx X0, X1, X2;
        radix3_combine(ar[zi][0],ai[zi][0],ar[zi][1],ai[zi][1],ar[zi][2],ai[zi][2],w1,w2,X0,X1,X2);
        S[k0][3*zg+zi] = X0; S[k1][3*zg+zi] = X1; S[k2][3*zg+zi] = X2;
    }
    __syncthreads();
}

// row DFT (second index, z), shifted, DIRECT coalesced global store:
// out[row*NN + k]; each 16-lane j-group stores consecutive elements.
__device__ __forceinline__ void dft_rows_g(cplx (*S)[NP], const cplx* W, int t,
                                           cplx* __restrict__ out) {
    const int rg = t >> 4;
    const int j  = t & 15;
    float ar[3][3], ai[3][3];
#pragma unroll
    for (int q = 0; q < 3; ++q)
#pragma unroll
        for (int r = 0; r < 3; ++r) { ar[q][r] = 0.f; ai[q][r] = 0.f; }
    const int step = 3 * j;
    int tw = 0;
#pragma unroll 4
    for (int n1 = 0; n1 < 16; ++n1) {
        cplx w = W[tw];
#pragma unroll
        for (int q = 0; q < 3; ++q) {
            const cplx* row = S[3*rg + q];
            cplx d0 = row[3*n1+0], d1 = row[3*n1+1], d2 = row[3*n1+2];
            CMAC(ar[q][0], ai[q][0], d0, w);
            CMAC(ar[q][1], ai[q][1], d1, w);
            CMAC(ar[q][2], ai[q][2], d2, w);
        }
        tw += step; if (tw >= NN) tw -= NN;
    }
    cplx w1 = W[j], w2 = W[2*j];
    int k0 = j + 24;                       // (j+24)%48
    int k1 = j + 40; if (k1 >= NN) k1 -= NN;
    int k2 = j + 8;
#pragma unroll
    for (int q = 0; q < 3; ++q) {
        cplx X0, X1, X2;
        radix3_combine(ar[q][0],ai[q][0],ar[q][1],ai[q][1],ar[q][2],ai[q][2],w1,w2,X0,X1,X2);
        cplx* row = out + (size_t)(3*rg + q) * NN;
        row[k0] = X0; row[k1] = X1; row[k2] = X2;
    }
}

// column DFT (first index), shifted, DIRECT global store:
// out[k*rstride + col], k < rlimit, scaled. (kB_f)
__device__ __forceinline__ void dft_cols_g(cplx (*S)[NP], const cplx* W, int t,
                                           cplx* __restrict__ out, int rstride,
                                           int rlimit, float scale) {
    const int zg = t & 15;
    const int j  = t >> 4;
    float ar[3][3], ai[3][3];
#pragma unroll
    for (int zi = 0; zi < 3; ++zi)
#pragma unroll
        for (int r = 0; r < 3; ++r) { ar[zi][r] = 0.f; ai[zi][r] = 0.f; }
    const int step = 3 * j;
    int tw = 0;
#pragma unroll 4
    for (int n1 = 0; n1 < 16; ++n1) {
        cplx w = W[tw];
#pragma unroll
        for (int r = 0; r < 3; ++r) {
            const cplx* row = S[3*n1 + r];
            cplx d0 = row[3*zg+0], d1 = row[3*zg+1], d2 = row[3*zg+2];
            CMAC(ar[0][r], ai[0][r], d0, w);
            CMAC(ar[1][r], ai[1][r], d1, w);
            CMAC(ar[2][r], ai[2][r], d2, w);
        }
        tw += step; if (tw >= NN) tw -= NN;
    }
    cplx w1 = W[j], w2 = W[2*j];
    int k0 = j + 24;            // (j+24)%48, j<16
    int k1 = j + 40; if (k1 >= NN) k1 -= NN;
    int k2 = j + 8;
#pragma unroll
    for (int zi = 0; zi < 3; ++zi) {
        cplx X0, X1, X2;
        radix3_combine(ar[zi][0],ai[zi][0],ar[zi][1],ai[zi][1],ar[zi][2],ai[zi][2],w1,w2,X0,X1,X2);
        int c = 3*zg + zi;
        if (k0 < rlimit) out[(size_t)k0*rstride + c] = make_float2(X0.x*scale, X0.y*scale);
        if (k1 < rlimit) out[(size_t)k1*rstride + c] = make_float2(X1.x*scale, X1.y*scale);
        if (k2 < rlimit) out[(size_t)k2*rstride + c] = make_float2(X2.x*scale, X2.y*scale);
    }
}

// ---------- float4 (dual complex) radix-3 DFT helpers (kAB) ----------
// column DFT (first index, y), in-LDS, no shift
__device__ __forceinline__ void dft_cols4(float4 (*S)[NP], const cplx* W, int t) {
    const int zg = t & 15;
    const int j  = t >> 4;
    float4 acc[3][3];   // [zi][r]
#pragma unroll
    for (int zi = 0; zi < 3; ++zi)
#pragma unroll
        for (int r = 0; r < 3; ++r) acc[zi][r] = make_float4(0.f,0.f,0.f,0.f);
    const int step = 3 * j;
    int tw = 0;
#pragma unroll 4
    for (int n1 = 0; n1 < 16; ++n1) {
        cplx w = W[tw];
#pragma unroll
        for (int r = 0; r < 3; ++r) {
            const float4* row = S[3*n1 + r];
            float4 d0 = row[3*zg+0], d1 = row[3*zg+1], d2 = row[3*zg+2];
            CMAC4(acc[0][r], d0, w);
            CMAC4(acc[1][r], d1, w);
            CMAC4(acc[2][r], d2, w);
        }
        tw += step; if (tw >= NN) tw -= NN;
    }
    cplx w1 = W[j], w2 = W[2*j];
    __syncthreads();
#pragma unroll
    for (int zi = 0; zi < 3; ++zi) {
        float4 X0, X1, X2;
        radix3_combine4(acc[zi][0], acc[zi][1], acc[zi][2], w1, w2, X0, X1, X2);
        S[j][3*zg+zi] = X0; S[j+16][3*zg+zi] = X1; S[j+32][3*zg+zi] = X2;
    }
    __syncthreads();
}

// row DFT (second index, z), no shift, DIRECT coalesced global store:
// out[row*NN + k]; 16-lane j-groups store 256B contiguous chunks.
__device__ __forceinline__ void dft_rows4_g(float4 (*S)[NP], const cplx* W, int t,
                                            float4* __restrict__ out) {
    const int rg = t >> 4;
    const int j  = t & 15;
    float4 acc[3][3];
#pragma unroll
    for (int q = 0; q < 3; ++q)
#pragma unroll
        for (int r = 0; r < 3; ++r) acc[q][r] = make_float4(0.f,0.f,0.f,0.f);
    const int step = 3 * j;
    int tw = 0;
    const float4* r0 = S[3*rg + 0];
    const float4* r1 = S[3*rg + 1];
    const float4* r2 = S[3*rg + 2];
#pragma unroll 4
    for (int n1 = 0; n1 < 16; ++n1) {
        cplx w = W[tw];
        float4 d00 = r0[3*n1+0], d01 = r0[3*n1+1], d02 = r0[3*n1+2];
        float4 d10 = r1[3*n1+0], d11 = r1[3*n1+1], d12 = r1[3*n1+2];
        float4 d20 = r2[3*n1+0], d21 = r2[3*n1+1], d22 = r2[3*n1+2];
        CMAC4(acc[0][0], d00, w); CMAC4(acc[0][1], d01, w); CMAC4(acc[0][2], d02, w);
        CMAC4(acc[1][0], d10, w); CMAC4(acc[1][1], d11, w); CMAC4(acc[1][2], d12, w);
        CMAC4(acc[2][0], d20, w); CMAC4(acc[2][1], d21, w); CMAC4(acc[2][2], d22, w);
        tw += step; if (tw >= NN) tw -= NN;
    }
    cplx w1 = W[j], w2 = W[2*j];
#pragma unroll
    for (int q = 0; q < 3; ++q) {
        float4 X0, X1, X2;
        radix3_combine4(acc[q][0], acc[q][1], acc[q][2], w1, w2, X0, X1, X2);
        float4* row = out + (size_t)(3*rg + q) * NN;
        row[j] = X0; row[j + 16] = X1; row[j + 32] = X2;
    }
}

// f (real) -> y-DFT (in LDS), z-DFT (direct store); both shifted
__global__ __launch_bounds__(256)
void kA_f(const float* __restrict__ f, cplx* __restrict__ out) {
    __shared__ cplx S[NN][NP];
    __shared__ cplx W[NN];
    const int x = blockIdx.x, b = blockIdx.y, t = threadIdx.x;
    const float* src = f + (size_t)b * N3 + (size_t)x * N2;
    for (int i = t; i < N2; i += 256) S[i / NN][i % NN] = make_float2(src[i], 0.f);
    twinit(W, t);
    __syncthreads();
    dft_cols(S, W, t, 1);                       // y-DFT, shifted
    cplx* dst = out + (size_t)b * N3 + (size_t)x * N2;
    dft_rows_g(S, W, t, dst);                   // z-DFT, shifted, direct store
}

// finalize f_spec: x-DFT (shifted), * 1/N3; direct store of ONLY the
// Hermitian half (k = 0..24) into compact spec_h[b][k][y][z].
__global__ __launch_bounds__(256)
void kB_f(const cplx* __restrict__ vol, cplx* __restrict__ outh) {
    __shared__ cplx S[NN][NP];
    __shared__ cplx W[NN];
    const int y = blockIdx.x, b = blockIdx.y, t = threadIdx.x;
    const cplx* base = vol + (size_t)b * N3 + (size_t)y * NN;
    for (int i = t; i < N2; i += 256) { int xr = i / NN, z = i % NN; S[xr][z] = base[(size_t)xr * N2 + z]; }
    twinit(W, t);
    __syncthreads();
    cplx* dst = outh + (size_t)b * NHN2 + (size_t)y * NN;
    dft_cols_g(S, W, t, dst, N2, NH, 1.f / (float)N3);
}

// Fused A-pass: va = F2(spec*phi), vb = F2(spec*psi) as dual-complex float4.
// y-DFT in LDS, z-DFT with direct coalesced store (3 barriers total).
// blockIdx.z = lt; ti = t0+lt; ti==NT -> fl pair (phipsi, identity).
__global__ __launch_bounds__(256)
void kAB(const cplx* __restrict__ spec,
         const float* __restrict__ phi, const float* __restrict__ psi,
         const float* __restrict__ phipsi,
         float4* __restrict__ vab, int t0) {
    __shared__ float4 S[NN][NP];
    __shared__ cplx W[NN];
    const int ix = blockIdx.x, b = blockIdx.y, lt = blockIdx.z, t = threadIdx.x;
    const int ti = t0 + lt;
    const cplx* src = spec + (size_t)b * NHN2 + (size_t)ix * N2;
    const float* mp;
    const float* mq;
    if (ti < NT) { mp = phi + (size_t)ti * N3 + (size_t)ix * N2; mq = psi + (size_t)ti * N3 + (size_t)ix * N2; }
    else         { mp = phipsi + (size_t)ix * N2;               mq = (const float*)nullptr; }
    for (int i = t; i < N2; i += 256) {
        cplx v = src[i];
        float p = mp[i];
        float q = mq ? mq[i] : 1.f;
        S[i / NN][i % NN] = make_float4(v.x * p, v.y * p, v.x * q, v.y * q);
    }
    twinit(W, t);
    __syncthreads();
    dft_cols4(S, W, t);                                       // y-DFT
    float4* out = vab + ((size_t)(lt * NB + b) * NH + ix) * N2;
    dft_rows4_g(S, W, t, out);                                // z-DFT, direct store
}

// Real-valued x-DFT via Hermitian symmetry + product + t-accumulate.
// Ah[j] = A[0] + (-1)^j A[24] + 2*sum_{n=1}^{23} Re(A[n] W48^{nj}).
// Register-prefetched tile staging (round-7, kept).
__global__ __launch_bounds__(256)
void kB_all(const float4* __restrict__ vab,
            float* __restrict__ out, const float* __restrict__ kn,
            const int* __restrict__ Mv, int t0, int cn) {
    __shared__ float4 SAB[NH][NN];   // 1200 float4, linear (2-way bank alias = free)
    __shared__ cplx W[NN];
    const int y = blockIdx.x, b = blockIdx.y, s = blockIdx.z, t = threadIdx.x;
    twinit(W, t);
    const int zg = t & 15, jg = t >> 4;
    const int i4 = 1024 + t;                 // 5th staged element index
    float4* SF = (float4*)SAB;
    float qr[3][3];
#pragma unroll
    for (int m = 0; m < 3; ++m)
#pragma unroll
        for (int zi = 0; zi < 3; ++zi) qr[m][zi] = 0.f;

    float4 R0, R1, R2, R3, R4;
    {   // prologue: stage first tile into regs
        const float4* base = vab + (size_t)(s * NB + b) * NH * N2 + (size_t)y * NN;
        R0 = base[(size_t)((t          ) / NN) * N2 + ((t          ) % NN)];
        R1 = base[(size_t)((t +  256   ) / NN) * N2 + ((t +  256   ) % NN)];
        R2 = base[(size_t)((t +  512   ) / NN) * N2 + ((t +  512   ) % NN)];
        R3 = base[(size_t)((t +  768   ) / NN) * N2 + ((t +  768   ) % NN)];
        if (i4 < NH * NN) R4 = base[(size_t)(i4 / NN) * N2 + (i4 % NN)];
    }

    for (int lt = s; lt < cn; lt += NSL) {
        const int ti = t0 + lt;
        SF[t]        = R0;
        SF[t +  256] = R1;
        SF[t +  512] = R2;
        SF[t +  768] = R3;
        if (i4 < NH * NN) SF[i4] = R4;
        __syncthreads();
        if (lt + NSL < cn) {
            const float4* base = vab + (size_t)((lt + NSL) * NB + b) * NH * N2 + (size_t)y * NN;
            R0 = base[(size_t)((t          ) / NN) * N2 + ((t          ) % NN)];
            R1 = base[(size_t)((t +  256   ) / NN) * N2 + ((t +  256   ) % NN)];
            R2 = base[(size_t)((t +  512   ) / NN) * N2 + ((t +  512   ) % NN)];
            R3 = base[(size_t)((t +  768   ) / NN) * N2 + ((t +  768   ) % NN)];
            if (i4 < NH * NN) R4 = base[(size_t)(i4 / NN) * N2 + (i4 % NN)];
        }
        float sa[3][3], sb[3][3];   // [m][zi]
#pragma unroll
        for (int m = 0; m < 3; ++m)
#pragma unroll
            for (int zi = 0; zi < 3; ++zi) { sa[m][zi] = 0.f; sb[m][zi] = 0.f; }
        int m0 = jg, m1 = jg + 16, m2 = jg + 32;
        const int s0 = jg, s1 = jg + 16, s2 = jg + 32;
        for (int n = 1; n <= 23; ++n) {
            cplx w0 = W[m0], w1 = W[m1], w2 = W[m2];
#pragma unroll
            for (int zi = 0; zi < 3; ++zi) {
                float4 d = SAB[n][3 * zg + zi];
                sa[0][zi] = fmaf(d.x, w0.x, sa[0][zi]); sa[0][zi] = fmaf(-d.y, w0.y, sa[0][zi]);
                sa[1][zi] = fmaf(d.x, w1.x, sa[1][zi]); sa[1][zi] = fmaf(-d.y, w1.y, sa[1][zi]);
                sa[2][zi] = fmaf(d.x, w2.x, sa[2][zi]); sa[2][zi] = fmaf(-d.y, w2.y, sa[2][zi]);
                sb[0][zi] = fmaf(d.z, w0.x, sb[0][zi]); sb[0][zi] = fmaf(-d.w, w0.y, sb[0][zi]);
                sb[1][zi] = fmaf(d.z, w1.x, sb[1][zi]); sb[1][zi] = fmaf(-d.w, w1.y, sb[1][zi]);
                sb[2][zi] = fmaf(d.z, w2.x, sb[2][zi]); sb[2][zi] = fmaf(-d.w, w2.y, sb[2][zi]);
            }
            m0 += s0; if (m0 >= NN) m0 -= NN;
            m1 += s1; if (m1 >= NN) m1 -= NN;
            m2 += s2; if (m2 >= NN) m2 -= NN;
        }
        const float sgn = (jg & 1) ? -1.f : 1.f;   // j = jg+16m, parity(j)=parity(jg)
        const float wgt = (ti == NT) ? -1.f : 1.f;
#pragma unroll
        for (int zi = 0; zi < 3; ++zi) {
            float4 e0  = SAB[0][3 * zg + zi];
            float4 e24 = SAB[24][3 * zg + zi];
            float basea = e0.x + sgn * e24.x;
            float baseb = e0.z + sgn * e24.z;
#pragma unroll
            for (int m = 0; m < 3; ++m) {
                float Ah = basea + 2.f * sa[m][zi];
                float Bh = baseb + 2.f * sb[m][zi];
                qr[m][zi] += wgt * Ah * Bh;
            }
        }
        __syncthreads();   // protect SAB before next iteration's ds_write
    }
    float mf = (float)(Mv[0] * Mv[0]);
    float scale = 4.f * 3.14159265358979323846f * 3.14159265358979323846f / (kn[0] * mf);
#pragma unroll
    for (int m = 0; m < 3; ++m) {
        int j = jg + 16 * m;
#pragma unroll
        for (int zi = 0; zi < 3; ++zi) {
            int z = 3 * zg + zi;
            size_t idx = (size_t)b * N3 + (size_t)j * N2 + (size_t)y * NN + z;
            atomicAdd(&out[idx], scale * qr[m][zi]);
        }
    }
}

extern "C" void kernel_launch(void* const* d_in, const int* in_sizes, int n_in,
                              void* d_out, int out_size, void* d_ws, size_t ws_size,
                              hipStream_t stream) {
    const float* f      = (const float*)d_in[0];
    const float* kn     = (const float*)d_in[1];
    const float* phi    = (const float*)d_in[2];
    const float* psi    = (const float*)d_in[3];
    const float* phipsi = (const float*)d_in[4];
    const int*   Mv     = (const int*)d_in[5];
    float* out = (float*)d_out;

    char* w = (char*)d_ws;
    const size_t fspecB = (size_t)NB * N3 * sizeof(cplx);            // 7,077,888
    const size_t spechB = (size_t)NB * NHN2 * sizeof(cplx);          // 3,686,400
    const size_t perTB  = (size_t)NB * NH * N2 * sizeof(float4);     // 7,372,800 per t
    cplx* fspec = (cplx*)w;
    cplx* spech = (cplx*)(w + fspecB);
    char* pool  = w + fspecB + spechB;

    const int NTOT = NT + 1;   // 20 fg terms + 1 fl term
    size_t head = fspecB + spechB;
    size_t avail = (ws_size > head) ? (ws_size - head) : 0;
    int chunk = (int)(avail / perTB);
    if (chunk < 1)    chunk = 1;
    if (chunk > NTOT) chunk = NTOT;
    float4* vab = (float4*)pool;

    hipMemsetAsync(out, 0, (size_t)NB * N3 * sizeof(float), stream);

    kA_f<<<dim3(NN, NB), 256, 0, stream>>>(f, fspec);
    kB_f<<<dim3(NN, NB), 256, 0, stream>>>(fspec, spech);

    for (int t0 = 0; t0 < NTOT; t0 += chunk) {
        int cn = (t0 + chunk <= NTOT) ? chunk : (NTOT - t0);
        kAB<<<dim3(NH, NB, cn), 256, 0, stream>>>(spech, phi, psi, phipsi, vab, t0);
        int zb = (cn < NSL) ? cn : NSL;
        kB_all<<<dim3(NN, NB, zb), 256, 0, stream>>>(vab, out, kn, Mv, t0, cn);
    }
}